// Round 1
// baseline (658.867 us; speedup 1.0000x reference)
//
#include <hip/hip_runtime.h>
#include <hip/hip_bf16.h>

// Problem constants
#define BB 8
#define NN 4096
#define EE 65536            // edges per graph
#define BE (BB*EE)          // 524288 total edges
#define BN (BB*NN)          // 32768 total nodes
#define INF 128
#define HID 512
#define CC 2
#define OUTC 10

// ---------------------------------------------------------------------------
// Kernel B: edge scatter  agg[dst,:] += w * x[src,:]  and  d[src] += w
// 2 edges per 256-thread block; 128 lanes per edge (one feature each).
// ---------------------------------------------------------------------------
__global__ __launch_bounds__(256) void edge_scatter(
    const int* __restrict__ src, const int* __restrict__ dst,
    const float* __restrict__ ew, const float* __restrict__ x,
    float* __restrict__ agg, float* __restrict__ dw) {
  int tid = threadIdx.x;
  int e = blockIdx.x * 2 + (tid >> 7);
  if (e >= BE) return;
  int lane = tid & 127;
  int s = src[e], d = dst[e];
  float w = ew[e];
  atomicAdd(&agg[d * INF + lane], w * x[s * INF + lane]);
  if (lane == 0) atomicAdd(&dw[s], w);
}

// ---------------------------------------------------------------------------
// Kernel C: fused GEMM  h = relu([agg|x](32768x256) @ [Wrel1;Wroot1](256x512) + b)
// 64x64 tile per 256-thread block, 4x4 micro-tile per thread, fp32.
// ---------------------------------------------------------------------------
__global__ __launch_bounds__(256) void gemm1(
    const float* __restrict__ agg, const float* __restrict__ x,
    const float* __restrict__ Wrel, const float* __restrict__ Wroot,
    const float* __restrict__ brel, float* __restrict__ h) {
  __shared__ float As[16][64];   // [k][row]
  __shared__ float Bs[16][64];   // [k][col]
  int tid = threadIdx.x;
  int bx = blockIdx.x % 8;       // col tile (512/64)
  int by = blockIdx.x / 8;       // row tile (32768/64)
  int tx = tid % 16, ty = tid / 16;
  int arow = tid >> 2;           // 0..63
  int akoff = (tid & 3) * 4;     // 0,4,8,12
  int brow = tid >> 4;           // 0..15
  int bcol = (tid & 15) * 4;     // 0..60
  int grow = by * 64 + arow;
  float acc[4][4];
#pragma unroll
  for (int i = 0; i < 4; ++i)
#pragma unroll
    for (int j = 0; j < 4; ++j) acc[i][j] = 0.f;

  for (int kc = 0; kc < 256; kc += 16) {
    // load A-tile (virtual concat of agg|x)
    int ka = kc + akoff;
    const float* Asrc = (ka < 128) ? (agg + grow * INF + ka)
                                   : (x + grow * INF + (ka - 128));
    float4 av = *(const float4*)Asrc;
    As[akoff + 0][arow] = av.x;
    As[akoff + 1][arow] = av.y;
    As[akoff + 2][arow] = av.z;
    As[akoff + 3][arow] = av.w;
    // load B-tile (virtual concat of Wrel1;Wroot1)
    int kb = kc + brow;
    const float* Bsrc = (kb < 128) ? (Wrel + kb * HID + bx * 64 + bcol)
                                   : (Wroot + (kb - 128) * HID + bx * 64 + bcol);
    *(float4*)&Bs[brow][bcol] = *(const float4*)Bsrc;
    __syncthreads();
#pragma unroll
    for (int k = 0; k < 16; ++k) {
      float4 a = *(const float4*)&As[k][ty * 4];
      float4 bq = *(const float4*)&Bs[k][tx * 4];
      acc[0][0] += a.x * bq.x; acc[0][1] += a.x * bq.y; acc[0][2] += a.x * bq.z; acc[0][3] += a.x * bq.w;
      acc[1][0] += a.y * bq.x; acc[1][1] += a.y * bq.y; acc[1][2] += a.y * bq.z; acc[1][3] += a.y * bq.w;
      acc[2][0] += a.z * bq.x; acc[2][1] += a.z * bq.y; acc[2][2] += a.z * bq.z; acc[2][3] += a.z * bq.w;
      acc[3][0] += a.w * bq.x; acc[3][1] += a.w * bq.y; acc[3][2] += a.w * bq.z; acc[3][3] += a.w * bq.w;
    }
    __syncthreads();
  }
  int col0 = bx * 64 + tx * 4;
  float4 bias = *(const float4*)&brel[col0];
#pragma unroll
  for (int i = 0; i < 4; ++i) {
    int r = by * 64 + ty * 4 + i;
    float4 o;
    o.x = fmaxf(acc[i][0] + bias.x, 0.f);
    o.y = fmaxf(acc[i][1] + bias.y, 0.f);
    o.z = fmaxf(acc[i][2] + bias.z, 0.f);
    o.w = fmaxf(acc[i][3] + bias.w, 0.f);
    *(float4*)&h[r * HID + col0] = o;
  }
}

// ---------------------------------------------------------------------------
// Kernel D: s_logits = h @ W_pool + b_pool ; s = softmax(s_logits)
// one wave (64 lanes) per node; 8 strided features per lane.
// ---------------------------------------------------------------------------
__global__ __launch_bounds__(256) void pool_softmax(
    const float* __restrict__ h, const float* __restrict__ Wp,
    const float* __restrict__ bp, float* __restrict__ s,
    float* __restrict__ slog) {
  __shared__ float wp0[HID], wp1[HID];
  int tid = threadIdx.x;
  for (int i = tid; i < HID; i += 256) {
    wp0[i] = Wp[i * 2];
    wp1[i] = Wp[i * 2 + 1];
  }
  __syncthreads();
  int wave = tid >> 6, lane = tid & 63;
  int n = blockIdx.x * 4 + wave;
  float acc0 = 0.f, acc1 = 0.f;
#pragma unroll
  for (int j = 0; j < 8; ++j) {
    int f = lane + j * 64;
    float hv = h[n * HID + f];
    acc0 += hv * wp0[f];
    acc1 += hv * wp1[f];
  }
#pragma unroll
  for (int off = 32; off; off >>= 1) {
    acc0 += __shfl_down(acc0, off, 64);
    acc1 += __shfl_down(acc1, off, 64);
  }
  if (lane == 0) {
    float l0 = acc0 + bp[0], l1 = acc1 + bp[1];
    slog[n * 2] = l0;
    slog[n * 2 + 1] = l1;
    float m = fmaxf(l0, l1);
    float e0 = expf(l0 - m), e1 = expf(l1 - m);
    float inv = 1.f / (e0 + e1);
    s[n * 2] = e0 * inv;
    s[n * 2 + 1] = e1 * inv;
  }
}

// ---------------------------------------------------------------------------
// Kernel E: out_adj_raw[b,i,j] = sum_e w_e * s[src,i] * s[dst,j]
// 64 blocks per graph, block-level reduction, 4 atomics per block.
// ---------------------------------------------------------------------------
__global__ __launch_bounds__(256) void edge_pass2(
    const int* __restrict__ src, const int* __restrict__ dst,
    const float* __restrict__ ew, const float* __restrict__ s,
    float* __restrict__ oadj) {
  int b = blockIdx.x >> 6;
  int sub = blockIdx.x & 63;
  int base = b * EE + sub * 1024;
  float p00 = 0, p01 = 0, p10 = 0, p11 = 0;
  for (int i = threadIdx.x; i < 1024; i += 256) {
    int e = base + i;
    int r = src[e], c = dst[e];
    float w = ew[e];
    float s0r = s[r * 2], s1r = s[r * 2 + 1];
    float s0c = s[c * 2], s1c = s[c * 2 + 1];
    p00 += w * s0r * s0c; p01 += w * s0r * s1c;
    p10 += w * s1r * s0c; p11 += w * s1r * s1c;
  }
#pragma unroll
  for (int off = 32; off; off >>= 1) {
    p00 += __shfl_down(p00, off, 64);
    p01 += __shfl_down(p01, off, 64);
    p10 += __shfl_down(p10, off, 64);
    p11 += __shfl_down(p11, off, 64);
  }
  __shared__ float red[4][4];
  int wave = threadIdx.x >> 6, lane = threadIdx.x & 63;
  if (lane == 0) {
    red[wave][0] = p00; red[wave][1] = p01;
    red[wave][2] = p10; red[wave][3] = p11;
  }
  __syncthreads();
  if (threadIdx.x < 4) {
    float v = red[0][threadIdx.x] + red[1][threadIdx.x] +
              red[2][threadIdx.x] + red[3][threadIdx.x];
    atomicAdd(&oadj[b * 4 + threadIdx.x], v);
  }
}

// ---------------------------------------------------------------------------
// Kernel F: out[b,c,:] += s[n,c]*h[n,:] ; ss accumulators ; mincut_den
// 256 nodes per block (one graph), thread t owns features t and t+256.
// ---------------------------------------------------------------------------
__global__ __launch_bounds__(256) void node_acc(
    const float* __restrict__ h, const float* __restrict__ s,
    const float* __restrict__ dw, float* __restrict__ outp,
    float* __restrict__ ssacc, float* __restrict__ mden) {
  int blk = blockIdx.x;            // 128 blocks
  int b = blk >> 4;                // 16 blocks per graph
  int n0 = blk * 256;
  int t = threadIdx.x;
  float a00 = 0, a01 = 0, a10 = 0, a11 = 0;
  float sa = 0, sb = 0, scv = 0, md = 0;
  for (int i = 0; i < 256; ++i) {
    int n = n0 + i;
    float s0 = s[n * 2], s1 = s[n * 2 + 1];
    float h0 = h[n * HID + t], h1 = h[n * HID + t + 256];
    a00 += s0 * h0; a01 += s0 * h1;
    a10 += s1 * h0; a11 += s1 * h1;
    if (t == 0) {
      float dn = dw[n];
      sa += s0 * s0; sb += s0 * s1; scv += s1 * s1;
      md += dn * (s0 * s0 + s1 * s1);
    }
  }
  atomicAdd(&outp[b * 1024 + t], a00);
  atomicAdd(&outp[b * 1024 + t + 256], a01);
  atomicAdd(&outp[b * 1024 + 512 + t], a10);
  atomicAdd(&outp[b * 1024 + 512 + t + 256], a11);
  if (t == 0) {
    atomicAdd(&ssacc[b * 4 + 0], sa);
    atomicAdd(&ssacc[b * 4 + 1], sb);
    atomicAdd(&ssacc[b * 4 + 2], scv);
    atomicAdd(&mden[b], md);
  }
}

// ---------------------------------------------------------------------------
// Kernel G: losses, out_adj normalization, conv3 + mean + lin1 + lin2 +
// log_softmax. One block per graph.
// ---------------------------------------------------------------------------
__global__ __launch_bounds__(256) void finalize(
    const float* __restrict__ outp, const float* __restrict__ oadj,
    const float* __restrict__ ssacc, const float* __restrict__ mden,
    const float* __restrict__ Wrel3, const float* __restrict__ brel3,
    const float* __restrict__ Wroot3, const float* __restrict__ Wlin1,
    const float* __restrict__ blin1, const float* __restrict__ Wlin2,
    const float* __restrict__ blin2, float* __restrict__ dout) {
  __shared__ float u[HID], v[HID], xm[HID], h2[HID], lg[OUTC], sc[4];
  int b = blockIdx.x, t = threadIdx.x;
  if (t == 0) {
    float r00 = oadj[b * 4 + 0], r01 = oadj[b * 4 + 1];
    float r10 = oadj[b * 4 + 2], r11 = oadj[b * 4 + 3];
    // mincut loss: mean over graphs of -(trace/den)
    atomicAdd(&dout[80], -((r00 + r11) / mden[b]) / (float)BB);
    // ortho loss
    float a = ssacc[b * 4 + 0], bb = ssacc[b * 4 + 1], c = ssacc[b * 4 + 2];
    float nrm = sqrtf(a * a + 2.f * bb * bb + c * c);
    float q = 0.70710678118654752f;   // 1/sqrt(C), C=2
    float da = a / nrm - q, db = bb / nrm, dc = c / nrm - q;
    atomicAdd(&dout[81], sqrtf(da * da + 2.f * db * db + dc * dc) / (float)BB);
    // normalized out_adj (diag zeroed)
    float d20 = sqrtf(r01) + 1e-15f;
    float d21 = sqrtf(r10) + 1e-15f;
    float oa01 = r01 / (d20 * d21);
    float oa10 = r10 / (d21 * d20);
    dout[65618 + b * 4 + 0] = 0.f;
    dout[65618 + b * 4 + 1] = oa01;
    dout[65618 + b * 4 + 2] = oa10;
    dout[65618 + b * 4 + 3] = 0.f;
    sc[0] = oa01; sc[1] = oa10;
  }
  __syncthreads();
  float oa01 = sc[0], oa10 = sc[1];
  // u = agg3[0]+agg3[1], v = out[0]+out[1]
  for (int f = t; f < HID; f += 256) {
    float o0 = outp[b * 1024 + f];
    float o1 = outp[b * 1024 + 512 + f];
    u[f] = oa10 * o1 + oa01 * o0;   // agg3[0]=oa[1][0]*out[1], agg3[1]=oa[0][1]*out[0]
    v[f] = o0 + o1;
  }
  __syncthreads();
  // xm[f] = 0.5*(u . Wrel3[:,f] + v . Wroot3[:,f]) + brel3[f]
  for (int f = t; f < HID; f += 256) {
    float acc = 0.f;
#pragma unroll 8
    for (int k = 0; k < HID; ++k)
      acc += u[k] * Wrel3[k * HID + f] + v[k] * Wroot3[k * HID + f];
    xm[f] = 0.5f * acc + brel3[f];
  }
  __syncthreads();
  for (int f = t; f < HID; f += 256) {
    float acc = blin1[f];
#pragma unroll 8
    for (int k = 0; k < HID; ++k) acc += xm[k] * Wlin1[k * HID + f];
    h2[f] = fmaxf(acc, 0.f);
  }
  __syncthreads();
  if (t < OUTC) {
    float acc = blin2[t];
#pragma unroll 8
    for (int k = 0; k < HID; ++k) acc += h2[k] * Wlin2[k * OUTC + t];
    lg[t] = acc;
  }
  __syncthreads();
  if (t == 0) {
    float m = lg[0];
    for (int o = 1; o < OUTC; ++o) m = fmaxf(m, lg[o]);
    float se = 0.f;
    for (int o = 0; o < OUTC; ++o) se += expf(lg[o] - m);
    sc[2] = m + logf(se);
  }
  __syncthreads();
  if (t < OUTC) dout[b * OUTC + t] = lg[t] - sc[2];
}

// ---------------------------------------------------------------------------
// Launcher
// ---------------------------------------------------------------------------
extern "C" void kernel_launch(void* const* d_in, const int* in_sizes, int n_in,
                              void* d_out, int out_size, void* d_ws, size_t ws_size,
                              hipStream_t stream) {
  const float* x      = (const float*)d_in[0];
  const int*   ei     = (const int*)d_in[1];
  const float* ew     = (const float*)d_in[3];
  const float* Wrel1  = (const float*)d_in[4];
  const float* brel1  = (const float*)d_in[5];
  const float* Wroot1 = (const float*)d_in[6];
  const float* Wpool  = (const float*)d_in[7];
  const float* bpool  = (const float*)d_in[8];
  const float* Wrel3  = (const float*)d_in[9];
  const float* brel3  = (const float*)d_in[10];
  const float* Wroot3 = (const float*)d_in[11];
  const float* Wlin1  = (const float*)d_in[12];
  const float* blin1  = (const float*)d_in[13];
  const float* Wlin2  = (const float*)d_in[14];
  const float* blin2  = (const float*)d_in[15];
  float* out = (float*)d_out;
  float* ws  = (float*)d_ws;

  // workspace layout (floats)
  float* agg   = ws;                       // 32768*128 = 4194304
  float* dw    = agg + 4194304;            // 32768
  float* outp  = dw + 32768;               // 8*2*512 = 8192
  float* oadj  = outp + 8192;              // 32
  float* ssacc = oadj + 32;                // 32
  float* mden  = ssacc + 32;               // 8
  float* h     = mden + 8;                 // 32768*512 = 16777216 (index 4235336, 16B aligned)
  float* s     = h + 16777216;             // 65536
  // total: 21,078,088 floats = 84.3 MB

  const int* src = ei;
  const int* dst = ei + BE;

  // zero all accumulators (agg..mden contiguous) and the two loss scalars
  hipMemsetAsync(ws, 0, (size_t)4235336 * sizeof(float), stream);
  hipMemsetAsync(out + 80, 0, 2 * sizeof(float), stream);

  edge_scatter<<<BE / 2, 256, 0, stream>>>(src, dst, ew, x, agg, dw);
  gemm1<<<(BN / 64) * (HID / 64), 256, 0, stream>>>(agg, x, Wrel1, Wroot1, brel1, h);
  pool_softmax<<<BN / 4, 256, 0, stream>>>(h, Wpool, bpool, s, out + 82);
  edge_pass2<<<BB * 64, 256, 0, stream>>>(src, dst, ew, s, oadj);
  node_acc<<<BN / 256, 256, 0, stream>>>(h, s, dw, outp, ssacc, mden);
  finalize<<<BB, 256, 0, stream>>>(outp, oadj, ssacc, mden, Wrel3, brel3,
                                   Wroot3, Wlin1, blin1, Wlin2, blin2, out);
}

// Round 2
// 533.241 us; speedup vs baseline: 1.2356x; 1.2356x over previous
//
#include <hip/hip_runtime.h>
#include <hip/hip_bf16.h>

// Problem constants
#define BB 8
#define NN 4096
#define EE 65536            // edges per graph
#define BE (BB*EE)          // 524288 total edges
#define BN (BB*NN)          // 32768 total nodes
#define INF 128
#define HID 512
#define CC 2
#define OUTC 10

// ---------------------------------------------------------------------------
// Kernel A1: degree histogram by dst + weighted out-degree dw[src] += w
// ---------------------------------------------------------------------------
__global__ __launch_bounds__(256) void edge_count(
    const int* __restrict__ src, const int* __restrict__ dst,
    const float* __restrict__ ew, int* __restrict__ deg,
    float* __restrict__ dw) {
  int e = blockIdx.x * 256 + threadIdx.x;
  if (e >= BE) return;
  atomicAdd(&deg[dst[e]], 1);
  atomicAdd(&dw[src[e]], ew[e]);
}

// ---------------------------------------------------------------------------
// Kernel A2: exclusive prefix sum of deg[0..32767] -> off.  One 1024-thread
// block; each thread scans 32 contiguous entries, Hillis-Steele over partials.
// ---------------------------------------------------------------------------
__global__ __launch_bounds__(1024) void scan_kernel(
    const int* __restrict__ deg, int* __restrict__ off) {
  __shared__ int part[1024];
  int t = threadIdx.x;
  int local[32];
  int s = 0;
#pragma unroll
  for (int i = 0; i < 32; ++i) { local[i] = s; s += deg[t * 32 + i]; }
  part[t] = s;
  __syncthreads();
  for (int o = 1; o < 1024; o <<= 1) {
    int v = (t >= o) ? part[t - o] : 0;
    __syncthreads();
    part[t] += v;
    __syncthreads();
  }
  int base = (t == 0) ? 0 : part[t - 1];
#pragma unroll
  for (int i = 0; i < 32; ++i) off[t * 32 + i] = base + local[i];
}

// ---------------------------------------------------------------------------
// Kernel A3: bucket edges by dst.  off[d] is consumed as a cursor: after this
// kernel off[d] = inclusive end of bucket d (start = off[d] - deg[d]).
// ---------------------------------------------------------------------------
__global__ __launch_bounds__(256) void edge_bucket(
    const int* __restrict__ src, const int* __restrict__ dst,
    const float* __restrict__ ew, int* __restrict__ off,
    int* __restrict__ ebs, float* __restrict__ ebw) {
  int e = blockIdx.x * 256 + threadIdx.x;
  if (e >= BE) return;
  int d = dst[e];
  int p = atomicAdd(&off[d], 1);
  ebs[p] = src[e];
  ebw[p] = ew[e];
}

// ---------------------------------------------------------------------------
// Kernel A4: gather  agg[n,:] = sum_{e: dst=n} w_e * x[src_e,:]
// one wave per node; lane owns 2 features (float2); no atomics.
// ---------------------------------------------------------------------------
__global__ __launch_bounds__(256) void gather_agg(
    const int* __restrict__ off, const int* __restrict__ deg,
    const int* __restrict__ ebs, const float* __restrict__ ebw,
    const float* __restrict__ x, float* __restrict__ agg) {
  int n = blockIdx.x * 4 + (threadIdx.x >> 6);
  int lane = threadIdx.x & 63;
  int end = off[n];
  int beg = end - deg[n];
  float ax = 0.f, ay = 0.f;
  int i = beg;
  for (; i + 1 < end; i += 2) {
    int s0 = ebs[i], s1 = ebs[i + 1];
    float w0 = ebw[i], w1 = ebw[i + 1];
    float2 v0 = *(const float2*)&x[(size_t)s0 * INF + lane * 2];
    float2 v1 = *(const float2*)&x[(size_t)s1 * INF + lane * 2];
    ax += w0 * v0.x + w1 * v1.x;
    ay += w0 * v0.y + w1 * v1.y;
  }
  if (i < end) {
    int s0 = ebs[i];
    float w0 = ebw[i];
    float2 v0 = *(const float2*)&x[(size_t)s0 * INF + lane * 2];
    ax += w0 * v0.x;
    ay += w0 * v0.y;
  }
  float2 o; o.x = ax; o.y = ay;
  *(float2*)&agg[(size_t)n * INF + lane * 2] = o;
}

// ---------------------------------------------------------------------------
// Kernel C: fused GEMM  h = relu([agg|x](32768x256) @ [Wrel1;Wroot1](256x512) + b)
// 64x64 tile per 256-thread block, 4x4 micro-tile per thread, fp32.
// ---------------------------------------------------------------------------
__global__ __launch_bounds__(256) void gemm1(
    const float* __restrict__ agg, const float* __restrict__ x,
    const float* __restrict__ Wrel, const float* __restrict__ Wroot,
    const float* __restrict__ brel, float* __restrict__ h) {
  __shared__ float As[16][64];   // [k][row]
  __shared__ float Bs[16][64];   // [k][col]
  int tid = threadIdx.x;
  int bx = blockIdx.x % 8;       // col tile (512/64)
  int by = blockIdx.x / 8;       // row tile (32768/64)
  int tx = tid % 16, ty = tid / 16;
  int arow = tid >> 2;           // 0..63
  int akoff = (tid & 3) * 4;     // 0,4,8,12
  int brow = tid >> 4;           // 0..15
  int bcol = (tid & 15) * 4;     // 0..60
  int grow = by * 64 + arow;
  float acc[4][4];
#pragma unroll
  for (int i = 0; i < 4; ++i)
#pragma unroll
    for (int j = 0; j < 4; ++j) acc[i][j] = 0.f;

  for (int kc = 0; kc < 256; kc += 16) {
    int ka = kc + akoff;
    const float* Asrc = (ka < 128) ? (agg + grow * INF + ka)
                                   : (x + grow * INF + (ka - 128));
    float4 av = *(const float4*)Asrc;
    As[akoff + 0][arow] = av.x;
    As[akoff + 1][arow] = av.y;
    As[akoff + 2][arow] = av.z;
    As[akoff + 3][arow] = av.w;
    int kb = kc + brow;
    const float* Bsrc = (kb < 128) ? (Wrel + kb * HID + bx * 64 + bcol)
                                   : (Wroot + (kb - 128) * HID + bx * 64 + bcol);
    *(float4*)&Bs[brow][bcol] = *(const float4*)Bsrc;
    __syncthreads();
#pragma unroll
    for (int k = 0; k < 16; ++k) {
      float4 a = *(const float4*)&As[k][ty * 4];
      float4 bq = *(const float4*)&Bs[k][tx * 4];
      acc[0][0] += a.x * bq.x; acc[0][1] += a.x * bq.y; acc[0][2] += a.x * bq.z; acc[0][3] += a.x * bq.w;
      acc[1][0] += a.y * bq.x; acc[1][1] += a.y * bq.y; acc[1][2] += a.y * bq.z; acc[1][3] += a.y * bq.w;
      acc[2][0] += a.z * bq.x; acc[2][1] += a.z * bq.y; acc[2][2] += a.z * bq.z; acc[2][3] += a.z * bq.w;
      acc[3][0] += a.w * bq.x; acc[3][1] += a.w * bq.y; acc[3][2] += a.w * bq.z; acc[3][3] += a.w * bq.w;
    }
    __syncthreads();
  }
  int col0 = bx * 64 + tx * 4;
  float4 bias = *(const float4*)&brel[col0];
#pragma unroll
  for (int i = 0; i < 4; ++i) {
    int r = by * 64 + ty * 4 + i;
    float4 o;
    o.x = fmaxf(acc[i][0] + bias.x, 0.f);
    o.y = fmaxf(acc[i][1] + bias.y, 0.f);
    o.z = fmaxf(acc[i][2] + bias.z, 0.f);
    o.w = fmaxf(acc[i][3] + bias.w, 0.f);
    *(float4*)&h[r * HID + col0] = o;
  }
}

// ---------------------------------------------------------------------------
// Kernel D: s_logits = h @ W_pool + b_pool ; s = softmax(s_logits)
// ---------------------------------------------------------------------------
__global__ __launch_bounds__(256) void pool_softmax(
    const float* __restrict__ h, const float* __restrict__ Wp,
    const float* __restrict__ bp, float* __restrict__ s,
    float* __restrict__ slog) {
  __shared__ float wp0[HID], wp1[HID];
  int tid = threadIdx.x;
  for (int i = tid; i < HID; i += 256) {
    wp0[i] = Wp[i * 2];
    wp1[i] = Wp[i * 2 + 1];
  }
  __syncthreads();
  int wave = tid >> 6, lane = tid & 63;
  int n = blockIdx.x * 4 + wave;
  float acc0 = 0.f, acc1 = 0.f;
#pragma unroll
  for (int j = 0; j < 8; ++j) {
    int f = lane + j * 64;
    float hv = h[n * HID + f];
    acc0 += hv * wp0[f];
    acc1 += hv * wp1[f];
  }
#pragma unroll
  for (int off = 32; off; off >>= 1) {
    acc0 += __shfl_down(acc0, off, 64);
    acc1 += __shfl_down(acc1, off, 64);
  }
  if (lane == 0) {
    float l0 = acc0 + bp[0], l1 = acc1 + bp[1];
    slog[n * 2] = l0;
    slog[n * 2 + 1] = l1;
    float m = fmaxf(l0, l1);
    float e0 = expf(l0 - m), e1 = expf(l1 - m);
    float inv = 1.f / (e0 + e1);
    s[n * 2] = e0 * inv;
    s[n * 2 + 1] = e1 * inv;
  }
}

// ---------------------------------------------------------------------------
// Kernel E: out_adj_raw[b,i,j] = sum_e w_e * s[src,i] * s[dst,j]
// ---------------------------------------------------------------------------
__global__ __launch_bounds__(256) void edge_pass2(
    const int* __restrict__ src, const int* __restrict__ dst,
    const float* __restrict__ ew, const float* __restrict__ s,
    float* __restrict__ oadj) {
  int b = blockIdx.x >> 6;
  int sub = blockIdx.x & 63;
  int base = b * EE + sub * 1024;
  float p00 = 0, p01 = 0, p10 = 0, p11 = 0;
  for (int i = threadIdx.x; i < 1024; i += 256) {
    int e = base + i;
    int r = src[e], c = dst[e];
    float w = ew[e];
    float s0r = s[r * 2], s1r = s[r * 2 + 1];
    float s0c = s[c * 2], s1c = s[c * 2 + 1];
    p00 += w * s0r * s0c; p01 += w * s0r * s1c;
    p10 += w * s1r * s0c; p11 += w * s1r * s1c;
  }
#pragma unroll
  for (int off = 32; off; off >>= 1) {
    p00 += __shfl_down(p00, off, 64);
    p01 += __shfl_down(p01, off, 64);
    p10 += __shfl_down(p10, off, 64);
    p11 += __shfl_down(p11, off, 64);
  }
  __shared__ float red[4][4];
  int wave = threadIdx.x >> 6, lane = threadIdx.x & 63;
  if (lane == 0) {
    red[wave][0] = p00; red[wave][1] = p01;
    red[wave][2] = p10; red[wave][3] = p11;
  }
  __syncthreads();
  if (threadIdx.x < 4) {
    float v = red[0][threadIdx.x] + red[1][threadIdx.x] +
              red[2][threadIdx.x] + red[3][threadIdx.x];
    atomicAdd(&oadj[b * 4 + threadIdx.x], v);
  }
}

// ---------------------------------------------------------------------------
// Kernel F: out[b,c,:] += s[n,c]*h[n,:] ; ss accumulators ; mincut_den
// ---------------------------------------------------------------------------
__global__ __launch_bounds__(256) void node_acc(
    const float* __restrict__ h, const float* __restrict__ s,
    const float* __restrict__ dw, float* __restrict__ outp,
    float* __restrict__ ssacc, float* __restrict__ mden) {
  int blk = blockIdx.x;            // 128 blocks
  int b = blk >> 4;                // 16 blocks per graph
  int n0 = blk * 256;
  int t = threadIdx.x;
  float a00 = 0, a01 = 0, a10 = 0, a11 = 0;
  float sa = 0, sb = 0, scv = 0, md = 0;
  for (int i = 0; i < 256; ++i) {
    int n = n0 + i;
    float s0 = s[n * 2], s1 = s[n * 2 + 1];
    float h0 = h[n * HID + t], h1 = h[n * HID + t + 256];
    a00 += s0 * h0; a01 += s0 * h1;
    a10 += s1 * h0; a11 += s1 * h1;
    if (t == 0) {
      float dn = dw[n];
      sa += s0 * s0; sb += s0 * s1; scv += s1 * s1;
      md += dn * (s0 * s0 + s1 * s1);
    }
  }
  atomicAdd(&outp[b * 1024 + t], a00);
  atomicAdd(&outp[b * 1024 + t + 256], a01);
  atomicAdd(&outp[b * 1024 + 512 + t], a10);
  atomicAdd(&outp[b * 1024 + 512 + t + 256], a11);
  if (t == 0) {
    atomicAdd(&ssacc[b * 4 + 0], sa);
    atomicAdd(&ssacc[b * 4 + 1], sb);
    atomicAdd(&ssacc[b * 4 + 2], scv);
    atomicAdd(&mden[b], md);
  }
}

// ---------------------------------------------------------------------------
// Kernel G: losses, out_adj normalization, conv3 + mean + lin1 + lin2 +
// log_softmax. One block per graph.
// ---------------------------------------------------------------------------
__global__ __launch_bounds__(256) void finalize(
    const float* __restrict__ outp, const float* __restrict__ oadj,
    const float* __restrict__ ssacc, const float* __restrict__ mden,
    const float* __restrict__ Wrel3, const float* __restrict__ brel3,
    const float* __restrict__ Wroot3, const float* __restrict__ Wlin1,
    const float* __restrict__ blin1, const float* __restrict__ Wlin2,
    const float* __restrict__ blin2, float* __restrict__ dout) {
  __shared__ float u[HID], v[HID], xm[HID], h2[HID], lg[OUTC], sc[4];
  int b = blockIdx.x, t = threadIdx.x;
  if (t == 0) {
    float r00 = oadj[b * 4 + 0], r01 = oadj[b * 4 + 1];
    float r10 = oadj[b * 4 + 2], r11 = oadj[b * 4 + 3];
    atomicAdd(&dout[80], -((r00 + r11) / mden[b]) / (float)BB);
    float a = ssacc[b * 4 + 0], bb = ssacc[b * 4 + 1], c = ssacc[b * 4 + 2];
    float nrm = sqrtf(a * a + 2.f * bb * bb + c * c);
    float q = 0.70710678118654752f;   // 1/sqrt(C), C=2
    float da = a / nrm - q, db = bb / nrm, dc = c / nrm - q;
    atomicAdd(&dout[81], sqrtf(da * da + 2.f * db * db + dc * dc) / (float)BB);
    float d20 = sqrtf(r01) + 1e-15f;
    float d21 = sqrtf(r10) + 1e-15f;
    float oa01 = r01 / (d20 * d21);
    float oa10 = r10 / (d21 * d20);
    dout[65618 + b * 4 + 0] = 0.f;
    dout[65618 + b * 4 + 1] = oa01;
    dout[65618 + b * 4 + 2] = oa10;
    dout[65618 + b * 4 + 3] = 0.f;
    sc[0] = oa01; sc[1] = oa10;
  }
  __syncthreads();
  float oa01 = sc[0], oa10 = sc[1];
  for (int f = t; f < HID; f += 256) {
    float o0 = outp[b * 1024 + f];
    float o1 = outp[b * 1024 + 512 + f];
    u[f] = oa10 * o1 + oa01 * o0;
    v[f] = o0 + o1;
  }
  __syncthreads();
  for (int f = t; f < HID; f += 256) {
    float acc = 0.f;
#pragma unroll 8
    for (int k = 0; k < HID; ++k)
      acc += u[k] * Wrel3[k * HID + f] + v[k] * Wroot3[k * HID + f];
    xm[f] = 0.5f * acc + brel3[f];
  }
  __syncthreads();
  for (int f = t; f < HID; f += 256) {
    float acc = blin1[f];
#pragma unroll 8
    for (int k = 0; k < HID; ++k) acc += xm[k] * Wlin1[k * HID + f];
    h2[f] = fmaxf(acc, 0.f);
  }
  __syncthreads();
  if (t < OUTC) {
    float acc = blin2[t];
#pragma unroll 8
    for (int k = 0; k < HID; ++k) acc += h2[k] * Wlin2[k * OUTC + t];
    lg[t] = acc;
  }
  __syncthreads();
  if (t == 0) {
    float m = lg[0];
    for (int o = 1; o < OUTC; ++o) m = fmaxf(m, lg[o]);
    float se = 0.f;
    for (int o = 0; o < OUTC; ++o) se += expf(lg[o] - m);
    sc[2] = m + logf(se);
  }
  __syncthreads();
  if (t < OUTC) dout[b * OUTC + t] = lg[t] - sc[2];
}

// ---------------------------------------------------------------------------
// Launcher
// ---------------------------------------------------------------------------
extern "C" void kernel_launch(void* const* d_in, const int* in_sizes, int n_in,
                              void* d_out, int out_size, void* d_ws, size_t ws_size,
                              hipStream_t stream) {
  const float* x      = (const float*)d_in[0];
  const int*   ei     = (const int*)d_in[1];
  const float* ew     = (const float*)d_in[3];
  const float* Wrel1  = (const float*)d_in[4];
  const float* brel1  = (const float*)d_in[5];
  const float* Wroot1 = (const float*)d_in[6];
  const float* Wpool  = (const float*)d_in[7];
  const float* bpool  = (const float*)d_in[8];
  const float* Wrel3  = (const float*)d_in[9];
  const float* brel3  = (const float*)d_in[10];
  const float* Wroot3 = (const float*)d_in[11];
  const float* Wlin1  = (const float*)d_in[12];
  const float* blin1  = (const float*)d_in[13];
  const float* Wlin2  = (const float*)d_in[14];
  const float* blin2  = (const float*)d_in[15];
  float* out = (float*)d_out;
  float* ws  = (float*)d_ws;

  // workspace layout (floats) — total 21,078,088 floats = 84.3 MB (same as R1)
  float* dw    = ws;                       // 32768
  float* outp  = dw + 32768;               // 8192
  float* oadj  = outp + 8192;              // 32
  float* ssacc = oadj + 32;                // 32
  float* mden  = ssacc + 32;               // 8
  int*   deg   = (int*)(mden + 8);         // 32768   [zero region ends: 73800]
  int*   off   = deg + 32768;              // 32768   (scan overwrites; bucket turns it into inclusive ends)
  float* agg   = (float*)(off + 32768);    // 4194304 (idx 106568, 16B aligned)
  float* h     = agg + 4194304;            // 16777216 (idx 4300872, 16B aligned)
  // aliases (lifetimes verified by kernel ordering on the stream):
  int*   ebs   = (int*)h;                  // 524288 ints — dead before gemm1 writes h
  float* ebw   = (float*)h + 524288;       // 524288 floats — dead before gemm1 writes h
  float* s     = agg;                      // 65536 floats — agg dead after gemm1

  const int* src = ei;
  const int* dst = ei + BE;

  // zero dw/outp/oadj/ssacc/mden/deg (contiguous, 73800 floats) + loss scalars
  hipMemsetAsync(ws, 0, (size_t)73800 * sizeof(float), stream);
  hipMemsetAsync(out + 80, 0, 2 * sizeof(float), stream);

  edge_count <<<BE / 256, 256, 0, stream>>>(src, dst, ew, deg, dw);
  scan_kernel<<<1, 1024, 0, stream>>>(deg, off);
  edge_bucket<<<BE / 256, 256, 0, stream>>>(src, dst, ew, off, ebs, ebw);
  gather_agg <<<BN / 4, 256, 0, stream>>>(off, deg, ebs, ebw, x, agg);
  gemm1<<<(BN / 64) * (HID / 64), 256, 0, stream>>>(agg, x, Wrel1, Wroot1, brel1, h);
  pool_softmax<<<BN / 4, 256, 0, stream>>>(h, Wpool, bpool, s, out + 82);
  edge_pass2<<<BB * 64, 256, 0, stream>>>(src, dst, ew, s, oadj);
  node_acc<<<BN / 256, 256, 0, stream>>>(h, s, dw, outp, ssacc, mden);
  finalize<<<BB, 256, 0, stream>>>(outp, oadj, ssacc, mden, Wrel3, brel3,
                                   Wroot3, Wlin1, blin1, Wlin2, blin2, out);
}

// Round 3
// 461.246 us; speedup vs baseline: 1.4285x; 1.1561x over previous
//
#include <hip/hip_runtime.h>
#include <hip/hip_bf16.h>

// Problem constants
#define BB 8
#define NN 4096
#define EE 65536            // edges per graph
#define BE (BB*EE)          // 524288 total edges
#define BN (BB*NN)          // 32768 total nodes
#define INF 128
#define HID 512
#define CC 2
#define OUTC 10

// ---------------------------------------------------------------------------
// Kernel A1: degree histogram by dst + weighted out-degree dw[src] += w
// ---------------------------------------------------------------------------
__global__ __launch_bounds__(256) void edge_count(
    const int* __restrict__ src, const int* __restrict__ dst,
    const float* __restrict__ ew, int* __restrict__ deg,
    float* __restrict__ dw) {
  int e = blockIdx.x * 256 + threadIdx.x;
  if (e >= BE) return;
  atomicAdd(&deg[dst[e]], 1);
  atomicAdd(&dw[src[e]], ew[e]);
}

// ---------------------------------------------------------------------------
// Kernel A2: exclusive prefix sum of deg[0..32767] -> off.
// ---------------------------------------------------------------------------
__global__ __launch_bounds__(1024) void scan_kernel(
    const int* __restrict__ deg, int* __restrict__ off) {
  __shared__ int part[1024];
  int t = threadIdx.x;
  int local[32];
  int s = 0;
#pragma unroll
  for (int i = 0; i < 32; ++i) { local[i] = s; s += deg[t * 32 + i]; }
  part[t] = s;
  __syncthreads();
  for (int o = 1; o < 1024; o <<= 1) {
    int v = (t >= o) ? part[t - o] : 0;
    __syncthreads();
    part[t] += v;
    __syncthreads();
  }
  int base = (t == 0) ? 0 : part[t - 1];
#pragma unroll
  for (int i = 0; i < 32; ++i) off[t * 32 + i] = base + local[i];
}

// ---------------------------------------------------------------------------
// Kernel A3: bucket edges by dst. off becomes inclusive bucket ends.
// ---------------------------------------------------------------------------
__global__ __launch_bounds__(256) void edge_bucket(
    const int* __restrict__ src, const int* __restrict__ dst,
    const float* __restrict__ ew, int* __restrict__ off,
    int* __restrict__ ebs, float* __restrict__ ebw) {
  int e = blockIdx.x * 256 + threadIdx.x;
  if (e >= BE) return;
  int d = dst[e];
  int p = atomicAdd(&off[d], 1);
  ebs[p] = src[e];
  ebw[p] = ew[e];
}

// ---------------------------------------------------------------------------
// Kernel A4: gather  agg[n,:] = sum_{e: dst=n} w_e * x[src_e,:]
// ---------------------------------------------------------------------------
__global__ __launch_bounds__(256) void gather_agg(
    const int* __restrict__ off, const int* __restrict__ deg,
    const int* __restrict__ ebs, const float* __restrict__ ebw,
    const float* __restrict__ x, float* __restrict__ agg) {
  int n = blockIdx.x * 4 + (threadIdx.x >> 6);
  int lane = threadIdx.x & 63;
  int end = off[n];
  int beg = end - deg[n];
  float ax = 0.f, ay = 0.f;
  int i = beg;
  for (; i + 1 < end; i += 2) {
    int s0 = ebs[i], s1 = ebs[i + 1];
    float w0 = ebw[i], w1 = ebw[i + 1];
    float2 v0 = *(const float2*)&x[(size_t)s0 * INF + lane * 2];
    float2 v1 = *(const float2*)&x[(size_t)s1 * INF + lane * 2];
    ax += w0 * v0.x + w1 * v1.x;
    ay += w0 * v0.y + w1 * v1.y;
  }
  if (i < end) {
    int s0 = ebs[i];
    float w0 = ebw[i];
    float2 v0 = *(const float2*)&x[(size_t)s0 * INF + lane * 2];
    ax += w0 * v0.x;
    ay += w0 * v0.y;
  }
  float2 o; o.x = ax; o.y = ay;
  *(float2*)&agg[(size_t)n * INF + lane * 2] = o;
}

// ---------------------------------------------------------------------------
// Kernel C: fused GEMM  h = relu([agg|x](32768x256) @ [Wrel1;Wroot1](256x512) + b)
// ---------------------------------------------------------------------------
__global__ __launch_bounds__(256) void gemm1(
    const float* __restrict__ agg, const float* __restrict__ x,
    const float* __restrict__ Wrel, const float* __restrict__ Wroot,
    const float* __restrict__ brel, float* __restrict__ h) {
  __shared__ float As[16][64];   // [k][row]
  __shared__ float Bs[16][64];   // [k][col]
  int tid = threadIdx.x;
  int bx = blockIdx.x % 8;       // col tile (512/64)
  int by = blockIdx.x / 8;       // row tile (32768/64)
  int tx = tid % 16, ty = tid / 16;
  int arow = tid >> 2;           // 0..63
  int akoff = (tid & 3) * 4;     // 0,4,8,12
  int brow = tid >> 4;           // 0..15
  int bcol = (tid & 15) * 4;     // 0..60
  int grow = by * 64 + arow;
  float acc[4][4];
#pragma unroll
  for (int i = 0; i < 4; ++i)
#pragma unroll
    for (int j = 0; j < 4; ++j) acc[i][j] = 0.f;

  for (int kc = 0; kc < 256; kc += 16) {
    int ka = kc + akoff;
    const float* Asrc = (ka < 128) ? (agg + grow * INF + ka)
                                   : (x + grow * INF + (ka - 128));
    float4 av = *(const float4*)Asrc;
    As[akoff + 0][arow] = av.x;
    As[akoff + 1][arow] = av.y;
    As[akoff + 2][arow] = av.z;
    As[akoff + 3][arow] = av.w;
    int kb = kc + brow;
    const float* Bsrc = (kb < 128) ? (Wrel + kb * HID + bx * 64 + bcol)
                                   : (Wroot + (kb - 128) * HID + bx * 64 + bcol);
    *(float4*)&Bs[brow][bcol] = *(const float4*)Bsrc;
    __syncthreads();
#pragma unroll
    for (int k = 0; k < 16; ++k) {
      float4 a = *(const float4*)&As[k][ty * 4];
      float4 bq = *(const float4*)&Bs[k][tx * 4];
      acc[0][0] += a.x * bq.x; acc[0][1] += a.x * bq.y; acc[0][2] += a.x * bq.z; acc[0][3] += a.x * bq.w;
      acc[1][0] += a.y * bq.x; acc[1][1] += a.y * bq.y; acc[1][2] += a.y * bq.z; acc[1][3] += a.y * bq.w;
      acc[2][0] += a.z * bq.x; acc[2][1] += a.z * bq.y; acc[2][2] += a.z * bq.z; acc[2][3] += a.z * bq.w;
      acc[3][0] += a.w * bq.x; acc[3][1] += a.w * bq.y; acc[3][2] += a.w * bq.z; acc[3][3] += a.w * bq.w;
    }
    __syncthreads();
  }
  int col0 = bx * 64 + tx * 4;
  float4 bias = *(const float4*)&brel[col0];
#pragma unroll
  for (int i = 0; i < 4; ++i) {
    int r = by * 64 + ty * 4 + i;
    float4 o;
    o.x = fmaxf(acc[i][0] + bias.x, 0.f);
    o.y = fmaxf(acc[i][1] + bias.y, 0.f);
    o.z = fmaxf(acc[i][2] + bias.z, 0.f);
    o.w = fmaxf(acc[i][3] + bias.w, 0.f);
    *(float4*)&h[r * HID + col0] = o;
  }
}

// ---------------------------------------------------------------------------
// Kernel D: s_logits = h @ W_pool + b_pool ; s = softmax(s_logits)
// ---------------------------------------------------------------------------
__global__ __launch_bounds__(256) void pool_softmax(
    const float* __restrict__ h, const float* __restrict__ Wp,
    const float* __restrict__ bp, float* __restrict__ s,
    float* __restrict__ slog) {
  __shared__ float wp0[HID], wp1[HID];
  int tid = threadIdx.x;
  for (int i = tid; i < HID; i += 256) {
    wp0[i] = Wp[i * 2];
    wp1[i] = Wp[i * 2 + 1];
  }
  __syncthreads();
  int wave = tid >> 6, lane = tid & 63;
  int n = blockIdx.x * 4 + wave;
  float acc0 = 0.f, acc1 = 0.f;
#pragma unroll
  for (int j = 0; j < 8; ++j) {
    int f = lane + j * 64;
    float hv = h[n * HID + f];
    acc0 += hv * wp0[f];
    acc1 += hv * wp1[f];
  }
#pragma unroll
  for (int off = 32; off; off >>= 1) {
    acc0 += __shfl_down(acc0, off, 64);
    acc1 += __shfl_down(acc1, off, 64);
  }
  if (lane == 0) {
    float l0 = acc0 + bp[0], l1 = acc1 + bp[1];
    slog[n * 2] = l0;
    slog[n * 2 + 1] = l1;
    float m = fmaxf(l0, l1);
    float e0 = expf(l0 - m), e1 = expf(l1 - m);
    float inv = 1.f / (e0 + e1);
    s[n * 2] = e0 * inv;
    s[n * 2 + 1] = e1 * inv;
  }
}

// ---------------------------------------------------------------------------
// Kernel E: out_adj_raw[b,i,j] = sum_e w_e * s[src,i] * s[dst,j]
// ---------------------------------------------------------------------------
__global__ __launch_bounds__(256) void edge_pass2(
    const int* __restrict__ src, const int* __restrict__ dst,
    const float* __restrict__ ew, const float* __restrict__ s,
    float* __restrict__ oadj) {
  int b = blockIdx.x >> 6;
  int sub = blockIdx.x & 63;
  int base = b * EE + sub * 1024;
  float p00 = 0, p01 = 0, p10 = 0, p11 = 0;
  for (int i = threadIdx.x; i < 1024; i += 256) {
    int e = base + i;
    int r = src[e], c = dst[e];
    float w = ew[e];
    float s0r = s[r * 2], s1r = s[r * 2 + 1];
    float s0c = s[c * 2], s1c = s[c * 2 + 1];
    p00 += w * s0r * s0c; p01 += w * s0r * s1c;
    p10 += w * s1r * s0c; p11 += w * s1r * s1c;
  }
#pragma unroll
  for (int off = 32; off; off >>= 1) {
    p00 += __shfl_down(p00, off, 64);
    p01 += __shfl_down(p01, off, 64);
    p10 += __shfl_down(p10, off, 64);
    p11 += __shfl_down(p11, off, 64);
  }
  __shared__ float red[4][4];
  int wave = threadIdx.x >> 6, lane = threadIdx.x & 63;
  if (lane == 0) {
    red[wave][0] = p00; red[wave][1] = p01;
    red[wave][2] = p10; red[wave][3] = p11;
  }
  __syncthreads();
  if (threadIdx.x < 4) {
    float v = red[0][threadIdx.x] + red[1][threadIdx.x] +
              red[2][threadIdx.x] + red[3][threadIdx.x];
    atomicAdd(&oadj[b * 4 + threadIdx.x], v);
  }
}

// ---------------------------------------------------------------------------
// Kernel F: out[b,c,:] += s[n,c]*h[n,:] ; ss accumulators ; mincut_den
// ---------------------------------------------------------------------------
__global__ __launch_bounds__(256) void node_acc(
    const float* __restrict__ h, const float* __restrict__ s,
    const float* __restrict__ dw, float* __restrict__ outp,
    float* __restrict__ ssacc, float* __restrict__ mden) {
  int blk = blockIdx.x;            // 128 blocks
  int b = blk >> 4;                // 16 blocks per graph
  int n0 = blk * 256;
  int t = threadIdx.x;
  float a00 = 0, a01 = 0, a10 = 0, a11 = 0;
  float sa = 0, sb = 0, scv = 0, md = 0;
  for (int i = 0; i < 256; ++i) {
    int n = n0 + i;
    float s0 = s[n * 2], s1 = s[n * 2 + 1];
    float h0 = h[n * HID + t], h1 = h[n * HID + t + 256];
    a00 += s0 * h0; a01 += s0 * h1;
    a10 += s1 * h0; a11 += s1 * h1;
    if (t == 0) {
      float dn = dw[n];
      sa += s0 * s0; sb += s0 * s1; scv += s1 * s1;
      md += dn * (s0 * s0 + s1 * s1);
    }
  }
  atomicAdd(&outp[b * 1024 + t], a00);
  atomicAdd(&outp[b * 1024 + t + 256], a01);
  atomicAdd(&outp[b * 1024 + 512 + t], a10);
  atomicAdd(&outp[b * 1024 + 512 + t + 256], a11);
  if (t == 0) {
    atomicAdd(&ssacc[b * 4 + 0], sa);
    atomicAdd(&ssacc[b * 4 + 1], sb);
    atomicAdd(&ssacc[b * 4 + 2], scv);
    atomicAdd(&mden[b], md);
  }
}

// ---------------------------------------------------------------------------
// Kernel G1: per-graph scalars (losses, out_adj norm) + build u,v vectors.
// u = oa10*out[1] + oa01*out[0] (pre-agg3 sum), v = out[0]+out[1].
// ---------------------------------------------------------------------------
__global__ __launch_bounds__(256) void finalize_a(
    const float* __restrict__ outp, const float* __restrict__ oadj,
    const float* __restrict__ ssacc, const float* __restrict__ mden,
    float* __restrict__ uv, float* __restrict__ dout) {
  __shared__ float sc[2];
  int b = blockIdx.x, t = threadIdx.x;
  if (t == 0) {
    float r00 = oadj[b * 4 + 0], r01 = oadj[b * 4 + 1];
    float r10 = oadj[b * 4 + 2], r11 = oadj[b * 4 + 3];
    atomicAdd(&dout[80], -((r00 + r11) / mden[b]) / (float)BB);
    float a = ssacc[b * 4 + 0], bb = ssacc[b * 4 + 1], c = ssacc[b * 4 + 2];
    float nrm = sqrtf(a * a + 2.f * bb * bb + c * c);
    float q = 0.70710678118654752f;   // 1/sqrt(C), C=2
    float da = a / nrm - q, db = bb / nrm, dc = c / nrm - q;
    atomicAdd(&dout[81], sqrtf(da * da + 2.f * db * db + dc * dc) / (float)BB);
    float d20 = sqrtf(r01) + 1e-15f;
    float d21 = sqrtf(r10) + 1e-15f;
    float oa01 = r01 / (d20 * d21);
    float oa10 = r10 / (d21 * d20);
    dout[65618 + b * 4 + 0] = 0.f;
    dout[65618 + b * 4 + 1] = oa01;
    dout[65618 + b * 4 + 2] = oa10;
    dout[65618 + b * 4 + 3] = 0.f;
    sc[0] = oa01; sc[1] = oa10;
  }
  __syncthreads();
  float oa01 = sc[0], oa10 = sc[1];
  for (int f = t; f < HID; f += 256) {
    float o0 = outp[b * 1024 + f];
    float o1 = outp[b * 1024 + 512 + f];
    uv[b * HID + f] = oa10 * o1 + oa01 * o0;           // u
    uv[BB * HID + b * HID + f] = o0 + o1;              // v
  }
}

// ---------------------------------------------------------------------------
// Kernel G2: xm[b,f] = 0.5*(u.Wrel3[:,f] + v.Wroot3[:,f]) + brel3[f]
// grid = BB*8 blocks (8 col-chunks of 64); 4-way split-K inside the block.
// ---------------------------------------------------------------------------
__global__ __launch_bounds__(256) void conv3_xm(
    const float* __restrict__ uv, const float* __restrict__ Wrel3,
    const float* __restrict__ Wroot3, const float* __restrict__ brel3,
    float* __restrict__ xm) {
  __shared__ float us[HID], vs[HID];
  __shared__ float red[4][64];
  int b = blockIdx.x >> 3;
  int fc = blockIdx.x & 7;
  int t = threadIdx.x;
  for (int i = t; i < HID; i += 256) {
    us[i] = uv[b * HID + i];
    vs[i] = uv[BB * HID + b * HID + i];
  }
  __syncthreads();
  int f = fc * 64 + (t & 63);
  int kq = t >> 6;
  float acc = 0.f;
#pragma unroll 8
  for (int k = kq * 128; k < kq * 128 + 128; ++k)
    acc += us[k] * Wrel3[k * HID + f] + vs[k] * Wroot3[k * HID + f];
  red[kq][t & 63] = acc;
  __syncthreads();
  if (kq == 0) {
    float v2 = red[0][t] + red[1][t] + red[2][t] + red[3][t];
    xm[b * HID + f] = 0.5f * v2 + brel3[f];
  }
}

// ---------------------------------------------------------------------------
// Kernel G3: h2[b,f] = relu(xm[b,:].Wlin1[:,f] + blin1[f]) — same structure.
// ---------------------------------------------------------------------------
__global__ __launch_bounds__(256) void lin1_h2(
    const float* __restrict__ xm, const float* __restrict__ Wlin1,
    const float* __restrict__ blin1, float* __restrict__ h2) {
  __shared__ float xs[HID];
  __shared__ float red[4][64];
  int b = blockIdx.x >> 3;
  int fc = blockIdx.x & 7;
  int t = threadIdx.x;
  for (int i = t; i < HID; i += 256) xs[i] = xm[b * HID + i];
  __syncthreads();
  int f = fc * 64 + (t & 63);
  int kq = t >> 6;
  float acc = 0.f;
#pragma unroll 8
  for (int k = kq * 128; k < kq * 128 + 128; ++k)
    acc += xs[k] * Wlin1[k * HID + f];
  red[kq][t & 63] = acc;
  __syncthreads();
  if (kq == 0) {
    float v2 = red[0][t] + red[1][t] + red[2][t] + red[3][t] + blin1[f];
    h2[b * HID + f] = fmaxf(v2, 0.f);
  }
}

// ---------------------------------------------------------------------------
// Kernel G4: logits = h2 @ Wlin2 + b; log_softmax. One block per graph,
// one wave per ~3 outputs, 64-lane shuffle reduction over K.
// ---------------------------------------------------------------------------
__global__ __launch_bounds__(256) void head(
    const float* __restrict__ h2, const float* __restrict__ Wlin2,
    const float* __restrict__ blin2, float* __restrict__ dout) {
  __shared__ float hs[HID];
  __shared__ float lg[16];
  __shared__ float lse;
  int b = blockIdx.x, t = threadIdx.x;
  for (int i = t; i < HID; i += 256) hs[i] = h2[b * HID + i];
  __syncthreads();
  int wave = t >> 6, lane = t & 63;
  for (int o = wave; o < OUTC; o += 4) {
    float acc = 0.f;
    for (int k = lane; k < HID; k += 64)
      acc += hs[k] * Wlin2[k * OUTC + o];
#pragma unroll
    for (int off = 32; off; off >>= 1) acc += __shfl_down(acc, off, 64);
    if (lane == 0) lg[o] = acc + blin2[o];
  }
  __syncthreads();
  if (t == 0) {
    float m = lg[0];
    for (int o = 1; o < OUTC; ++o) m = fmaxf(m, lg[o]);
    float se = 0.f;
    for (int o = 0; o < OUTC; ++o) se += expf(lg[o] - m);
    lse = m + logf(se);
  }
  __syncthreads();
  if (t < OUTC) dout[b * OUTC + t] = lg[t] - lse;
}

// ---------------------------------------------------------------------------
// Launcher
// ---------------------------------------------------------------------------
extern "C" void kernel_launch(void* const* d_in, const int* in_sizes, int n_in,
                              void* d_out, int out_size, void* d_ws, size_t ws_size,
                              hipStream_t stream) {
  const float* x      = (const float*)d_in[0];
  const int*   ei     = (const int*)d_in[1];
  const float* ew     = (const float*)d_in[3];
  const float* Wrel1  = (const float*)d_in[4];
  const float* brel1  = (const float*)d_in[5];
  const float* Wroot1 = (const float*)d_in[6];
  const float* Wpool  = (const float*)d_in[7];
  const float* bpool  = (const float*)d_in[8];
  const float* Wrel3  = (const float*)d_in[9];
  const float* brel3  = (const float*)d_in[10];
  const float* Wroot3 = (const float*)d_in[11];
  const float* Wlin1  = (const float*)d_in[12];
  const float* blin1  = (const float*)d_in[13];
  const float* Wlin2  = (const float*)d_in[14];
  const float* blin2  = (const float*)d_in[15];
  float* out = (float*)d_out;
  float* ws  = (float*)d_ws;

  // workspace layout (floats) — total 21,078,088 floats = 84.3 MB (same as R2)
  float* dw    = ws;                       // 32768
  float* outp  = dw + 32768;               // 8192
  float* oadj  = outp + 8192;              // 32
  float* ssacc = oadj + 32;                // 32
  float* mden  = ssacc + 32;               // 8
  int*   deg   = (int*)(mden + 8);         // 32768   [zero region ends: 73800]
  int*   off   = deg + 32768;              // 32768
  float* agg   = (float*)(off + 32768);    // 4194304 (idx 106568, 16B aligned)
  float* h     = agg + 4194304;            // 16777216 (idx 4300872, 16B aligned)
  // aliases (lifetimes by stream order):
  int*   ebs   = (int*)h;                  // dead before gemm1 writes h
  float* ebw   = (float*)h + 524288;       // dead before gemm1 writes h
  float* s     = agg;                      // agg dead after gemm1
  float* uv    = (float*)deg;              // 8192 floats — deg dead after gather_agg
  float* xm    = (float*)off;              // 4096 floats — off dead after gather_agg
  float* h2    = (float*)off + 4096;       // 4096 floats

  const int* src = ei;
  const int* dst = ei + BE;

  hipMemsetAsync(ws, 0, (size_t)73800 * sizeof(float), stream);
  hipMemsetAsync(out + 80, 0, 2 * sizeof(float), stream);

  edge_count <<<BE / 256, 256, 0, stream>>>(src, dst, ew, deg, dw);
  scan_kernel<<<1, 1024, 0, stream>>>(deg, off);
  edge_bucket<<<BE / 256, 256, 0, stream>>>(src, dst, ew, off, ebs, ebw);
  gather_agg <<<BN / 4, 256, 0, stream>>>(off, deg, ebs, ebw, x, agg);
  gemm1<<<(BN / 64) * (HID / 64), 256, 0, stream>>>(agg, x, Wrel1, Wroot1, brel1, h);
  pool_softmax<<<BN / 4, 256, 0, stream>>>(h, Wpool, bpool, s, out + 82);
  edge_pass2<<<BB * 64, 256, 0, stream>>>(src, dst, ew, s, oadj);
  node_acc<<<BN / 256, 256, 0, stream>>>(h, s, dw, outp, ssacc, mden);
  finalize_a<<<BB, 256, 0, stream>>>(outp, oadj, ssacc, mden, uv, out);
  conv3_xm  <<<BB * 8, 256, 0, stream>>>(uv, Wrel3, Wroot3, brel3, xm);
  lin1_h2   <<<BB * 8, 256, 0, stream>>>(xm, Wlin1, blin1, h2);
  head      <<<BB, 256, 0, stream>>>(h2, Wlin2, blin2, out);
}

// Round 4
// 371.591 us; speedup vs baseline: 1.7731x; 1.2413x over previous
//
#include <hip/hip_runtime.h>
#include <hip/hip_bf16.h>

// Problem constants
#define BB 8
#define NN 4096
#define EE 65536            // edges per graph
#define BE (BB*EE)          // 524288 total edges
#define BN (BB*NN)          // 32768 total nodes
#define INF 128
#define HID 512
#define CC 2
#define OUTC 10

typedef __bf16 bf16x8_t __attribute__((ext_vector_type(8)));
typedef float  f32x4_t  __attribute__((ext_vector_type(4)));

__device__ __forceinline__ ushort f2bf(float f) {
  union { float f; unsigned u; } v; v.f = f;
  unsigned r = v.u + 0x7FFFu + ((v.u >> 16) & 1u);   // RNE
  return (ushort)(r >> 16);
}
__device__ __forceinline__ float bf2f(ushort s) {
  union { unsigned u; float f; } v; v.u = ((unsigned)s) << 16;
  return v.f;
}

// ---------------------------------------------------------------------------
// Kernel A1: degree histogram by dst + weighted out-degree dw[src] += w
// ---------------------------------------------------------------------------
__global__ __launch_bounds__(256) void edge_count(
    const int* __restrict__ src, const int* __restrict__ dst,
    const float* __restrict__ ew, int* __restrict__ deg,
    float* __restrict__ dw) {
  int e = blockIdx.x * 256 + threadIdx.x;
  if (e >= BE) return;
  atomicAdd(&deg[dst[e]], 1);
  atomicAdd(&dw[src[e]], ew[e]);
}

// ---------------------------------------------------------------------------
// Kernel A2: exclusive prefix sum of deg[0..32767] -> off.
// ---------------------------------------------------------------------------
__global__ __launch_bounds__(1024) void scan_kernel(
    const int* __restrict__ deg, int* __restrict__ off) {
  __shared__ int part[1024];
  int t = threadIdx.x;
  int local[32];
  int s = 0;
#pragma unroll
  for (int i = 0; i < 32; ++i) { local[i] = s; s += deg[t * 32 + i]; }
  part[t] = s;
  __syncthreads();
  for (int o = 1; o < 1024; o <<= 1) {
    int v = (t >= o) ? part[t - o] : 0;
    __syncthreads();
    part[t] += v;
    __syncthreads();
  }
  int base = (t == 0) ? 0 : part[t - 1];
#pragma unroll
  for (int i = 0; i < 32; ++i) off[t * 32 + i] = base + local[i];
}

// ---------------------------------------------------------------------------
// Kernel A3: bucket edges by dst. off becomes inclusive bucket ends.
// ---------------------------------------------------------------------------
__global__ __launch_bounds__(256) void edge_bucket(
    const int* __restrict__ src, const int* __restrict__ dst,
    const float* __restrict__ ew, int* __restrict__ off,
    int* __restrict__ ebs, float* __restrict__ ebw) {
  int e = blockIdx.x * 256 + threadIdx.x;
  if (e >= BE) return;
  int d = dst[e];
  int p = atomicAdd(&off[d], 1);
  ebs[p] = src[e];
  ebw[p] = ew[e];
}

// ---------------------------------------------------------------------------
// Kernel A4: gather  A[n, 0:128] = bf16( sum_{e: dst=n} w_e * x[src_e,:] )
// ---------------------------------------------------------------------------
__global__ __launch_bounds__(256) void gather_agg(
    const int* __restrict__ off, const int* __restrict__ deg,
    const int* __restrict__ ebs, const float* __restrict__ ebw,
    const float* __restrict__ x, ushort* __restrict__ Ab) {
  int n = blockIdx.x * 4 + (threadIdx.x >> 6);
  int lane = threadIdx.x & 63;
  int end = off[n];
  int beg = end - deg[n];
  float ax = 0.f, ay = 0.f;
  int i = beg;
  for (; i + 1 < end; i += 2) {
    int s0 = ebs[i], s1 = ebs[i + 1];
    float w0 = ebw[i], w1 = ebw[i + 1];
    float2 v0 = *(const float2*)&x[(size_t)s0 * INF + lane * 2];
    float2 v1 = *(const float2*)&x[(size_t)s1 * INF + lane * 2];
    ax += w0 * v0.x + w1 * v1.x;
    ay += w0 * v0.y + w1 * v1.y;
  }
  if (i < end) {
    int s0 = ebs[i];
    float w0 = ebw[i];
    float2 v0 = *(const float2*)&x[(size_t)s0 * INF + lane * 2];
    ax += w0 * v0.x;
    ay += w0 * v0.y;
  }
  ushort2 o; o.x = f2bf(ax); o.y = f2bf(ay);
  *(ushort2*)&Ab[(size_t)n * 256 + lane * 2] = o;
}

// ---------------------------------------------------------------------------
// Kernel A5: cast x -> A[:, 128:256] bf16.  One float4 per thread.
// ---------------------------------------------------------------------------
__global__ __launch_bounds__(256) void cast_x(
    const float* __restrict__ x, ushort* __restrict__ Ab) {
  int g = blockIdx.x * 256 + threadIdx.x;        // 0..1048575
  float4 v = *(const float4*)&x[(size_t)g * 4];
  int m = g >> 5;
  int kin = (g & 31) * 4;
  ushort4 o;
  o.x = f2bf(v.x); o.y = f2bf(v.y); o.z = f2bf(v.z); o.w = f2bf(v.w);
  *(ushort4*)&Ab[(size_t)m * 256 + 128 + kin] = o;
}

// ---------------------------------------------------------------------------
// Kernel A6: Bb[n][k] = bf16 of [Wrel1;Wroot1][k][n]  (pre-transposed weights)
// ---------------------------------------------------------------------------
__global__ __launch_bounds__(256) void cast_w(
    const float* __restrict__ Wrel, const float* __restrict__ Wroot,
    ushort* __restrict__ Bb) {
  int g = blockIdx.x * 256 + threadIdx.x;        // 0..131071
  int n = g & 511, k = g >> 9;
  float w = (k < 128) ? Wrel[k * 512 + n] : Wroot[(k - 128) * 512 + n];
  Bb[n * 256 + k] = f2bf(w);
}

// ---------------------------------------------------------------------------
// Kernel C: MFMA GEMM  h = relu(A(32768x256) @ B(256x512) + b), bf16 in/out.
// 128x128 tile per block, 4 waves (2x2 of 64x64), 16x16x32 bf16 MFMA, BK=32.
// A staged [m][k] (pad 40), B staged [n][k] (pad 40) -> all frags ds_read_b128.
// ---------------------------------------------------------------------------
#define LDA 40
__global__ __launch_bounds__(256) void gemm_mfma(
    const ushort* __restrict__ Ab, const ushort* __restrict__ Bb,
    const float* __restrict__ brel, ushort* __restrict__ hw) {
  __shared__ ushort As[128 * LDA];
  __shared__ ushort Bs[128 * LDA];
  int tid = threadIdx.x;
  int by = blockIdx.x >> 2;        // row tile (256)
  int bx = blockIdx.x & 3;         // col tile (4)
  int m0 = by * 128, n0 = bx * 128;
  int wave = tid >> 6, lane = tid & 63;
  int wm = (wave >> 1) * 64, wn = (wave & 1) * 64;
  int l16 = lane & 15, quad = lane >> 4;

  f32x4_t acc[4][4];
#pragma unroll
  for (int i = 0; i < 4; ++i)
#pragma unroll
    for (int j = 0; j < 4; ++j) acc[i][j] = (f32x4_t){0.f, 0.f, 0.f, 0.f};

  int r0 = tid >> 2,          k0 = (tid & 3) * 8;
  int r1 = (tid + 256) >> 2,  k1 = (tid & 3) * 8;   // p=tid+256: (p&3)==(tid&3)

  // precomputed fragment LDS offsets (bf16 units)
  int aoff[4], boff[4];
#pragma unroll
  for (int i = 0; i < 4; ++i) {
    aoff[i] = (wm + i * 16 + l16) * LDA + quad * 8;
    boff[i] = (wn + i * 16 + l16) * LDA + quad * 8;
  }

  for (int kc = 0; kc < 256; kc += 32) {
    *(uint4*)&As[r0 * LDA + k0] = *(const uint4*)&Ab[(size_t)(m0 + r0) * 256 + kc + k0];
    *(uint4*)&As[r1 * LDA + k1] = *(const uint4*)&Ab[(size_t)(m0 + r1) * 256 + kc + k1];
    *(uint4*)&Bs[r0 * LDA + k0] = *(const uint4*)&Bb[(size_t)(n0 + r0) * 256 + kc + k0];
    *(uint4*)&Bs[r1 * LDA + k1] = *(const uint4*)&Bb[(size_t)(n0 + r1) * 256 + kc + k1];
    __syncthreads();
    bf16x8_t af[4], bf[4];
#pragma unroll
    for (int i = 0; i < 4; ++i) {
      af[i] = *(const bf16x8_t*)&As[aoff[i]];
      bf[i] = *(const bf16x8_t*)&Bs[boff[i]];
    }
#pragma unroll
    for (int mt = 0; mt < 4; ++mt)
#pragma unroll
      for (int nt = 0; nt < 4; ++nt)
        acc[mt][nt] = __builtin_amdgcn_mfma_f32_16x16x32_bf16(af[mt], bf[nt], acc[mt][nt], 0, 0, 0);
    __syncthreads();
  }

#pragma unroll
  for (int nt = 0; nt < 4; ++nt) {
    int col = n0 + wn + nt * 16 + l16;
    float bias = brel[col];
#pragma unroll
    for (int mt = 0; mt < 4; ++mt) {
      int rowb = m0 + wm + mt * 16 + quad * 4;
#pragma unroll
      for (int r = 0; r < 4; ++r) {
        float v = fmaxf(acc[mt][nt][r] + bias, 0.f);
        hw[(size_t)(rowb + r) * 512 + col] = f2bf(v);
      }
    }
  }
}

// ---------------------------------------------------------------------------
// Kernel D: s_logits = h @ W_pool + b_pool ; s = softmax(s_logits). h is bf16.
// ---------------------------------------------------------------------------
__global__ __launch_bounds__(256) void pool_softmax(
    const ushort* __restrict__ hw, const float* __restrict__ Wp,
    const float* __restrict__ bp, float* __restrict__ s,
    float* __restrict__ slog) {
  __shared__ float wp0[HID], wp1[HID];
  int tid = threadIdx.x;
  for (int i = tid; i < HID; i += 256) {
    wp0[i] = Wp[i * 2];
    wp1[i] = Wp[i * 2 + 1];
  }
  __syncthreads();
  int wave = tid >> 6, lane = tid & 63;
  int n = blockIdx.x * 4 + wave;
  float acc0 = 0.f, acc1 = 0.f;
#pragma unroll
  for (int j = 0; j < 8; ++j) {
    int f = lane + j * 64;
    float hv = bf2f(hw[(size_t)n * HID + f]);
    acc0 += hv * wp0[f];
    acc1 += hv * wp1[f];
  }
#pragma unroll
  for (int off = 32; off; off >>= 1) {
    acc0 += __shfl_down(acc0, off, 64);
    acc1 += __shfl_down(acc1, off, 64);
  }
  if (lane == 0) {
    float l0 = acc0 + bp[0], l1 = acc1 + bp[1];
    slog[n * 2] = l0;
    slog[n * 2 + 1] = l1;
    float m = fmaxf(l0, l1);
    float e0 = expf(l0 - m), e1 = expf(l1 - m);
    float inv = 1.f / (e0 + e1);
    s[n * 2] = e0 * inv;
    s[n * 2 + 1] = e1 * inv;
  }
}

// ---------------------------------------------------------------------------
// Kernel E: out_adj_raw[b,i,j] = sum_e w_e * s[src,i] * s[dst,j]
// ---------------------------------------------------------------------------
__global__ __launch_bounds__(256) void edge_pass2(
    const int* __restrict__ src, const int* __restrict__ dst,
    const float* __restrict__ ew, const float* __restrict__ s,
    float* __restrict__ oadj) {
  int b = blockIdx.x >> 6;
  int sub = blockIdx.x & 63;
  int base = b * EE + sub * 1024;
  float p00 = 0, p01 = 0, p10 = 0, p11 = 0;
  for (int i = threadIdx.x; i < 1024; i += 256) {
    int e = base + i;
    int r = src[e], c = dst[e];
    float w = ew[e];
    float s0r = s[r * 2], s1r = s[r * 2 + 1];
    float s0c = s[c * 2], s1c = s[c * 2 + 1];
    p00 += w * s0r * s0c; p01 += w * s0r * s1c;
    p10 += w * s1r * s0c; p11 += w * s1r * s1c;
  }
#pragma unroll
  for (int off = 32; off; off >>= 1) {
    p00 += __shfl_down(p00, off, 64);
    p01 += __shfl_down(p01, off, 64);
    p10 += __shfl_down(p10, off, 64);
    p11 += __shfl_down(p11, off, 64);
  }
  __shared__ float red[4][4];
  int wave = threadIdx.x >> 6, lane = threadIdx.x & 63;
  if (lane == 0) {
    red[wave][0] = p00; red[wave][1] = p01;
    red[wave][2] = p10; red[wave][3] = p11;
  }
  __syncthreads();
  if (threadIdx.x < 4) {
    float v = red[0][threadIdx.x] + red[1][threadIdx.x] +
              red[2][threadIdx.x] + red[3][threadIdx.x];
    atomicAdd(&oadj[b * 4 + threadIdx.x], v);
  }
}

// ---------------------------------------------------------------------------
// Kernel F: out[b,c,:] += s[n,c]*h[n,:] ; ss accumulators ; mincut_den
// ---------------------------------------------------------------------------
__global__ __launch_bounds__(256) void node_acc(
    const ushort* __restrict__ hw, const float* __restrict__ s,
    const float* __restrict__ dw, float* __restrict__ outp,
    float* __restrict__ ssacc, float* __restrict__ mden) {
  int blk = blockIdx.x;            // 128 blocks
  int b = blk >> 4;
  int n0 = blk * 256;
  int t = threadIdx.x;
  float a00 = 0, a01 = 0, a10 = 0, a11 = 0;
  float sa = 0, sb = 0, scv = 0, md = 0;
  for (int i = 0; i < 256; ++i) {
    int n = n0 + i;
    float s0 = s[n * 2], s1 = s[n * 2 + 1];
    float h0 = bf2f(hw[(size_t)n * HID + t]);
    float h1 = bf2f(hw[(size_t)n * HID + t + 256]);
    a00 += s0 * h0; a01 += s0 * h1;
    a10 += s1 * h0; a11 += s1 * h1;
    if (t == 0) {
      float dn = dw[n];
      sa += s0 * s0; sb += s0 * s1; scv += s1 * s1;
      md += dn * (s0 * s0 + s1 * s1);
    }
  }
  atomicAdd(&outp[b * 1024 + t], a00);
  atomicAdd(&outp[b * 1024 + t + 256], a01);
  atomicAdd(&outp[b * 1024 + 512 + t], a10);
  atomicAdd(&outp[b * 1024 + 512 + t + 256], a11);
  if (t == 0) {
    atomicAdd(&ssacc[b * 4 + 0], sa);
    atomicAdd(&ssacc[b * 4 + 1], sb);
    atomicAdd(&ssacc[b * 4 + 2], scv);
    atomicAdd(&mden[b], md);
  }
}

// ---------------------------------------------------------------------------
// Kernel G1: per-graph scalars + build u,v vectors.
// ---------------------------------------------------------------------------
__global__ __launch_bounds__(256) void finalize_a(
    const float* __restrict__ outp, const float* __restrict__ oadj,
    const float* __restrict__ ssacc, const float* __restrict__ mden,
    float* __restrict__ uv, float* __restrict__ dout) {
  __shared__ float sc[2];
  int b = blockIdx.x, t = threadIdx.x;
  if (t == 0) {
    float r00 = oadj[b * 4 + 0], r01 = oadj[b * 4 + 1];
    float r10 = oadj[b * 4 + 2], r11 = oadj[b * 4 + 3];
    atomicAdd(&dout[80], -((r00 + r11) / mden[b]) / (float)BB);
    float a = ssacc[b * 4 + 0], bb = ssacc[b * 4 + 1], c = ssacc[b * 4 + 2];
    float nrm = sqrtf(a * a + 2.f * bb * bb + c * c);
    float q = 0.70710678118654752f;
    float da = a / nrm - q, db = bb / nrm, dc = c / nrm - q;
    atomicAdd(&dout[81], sqrtf(da * da + 2.f * db * db + dc * dc) / (float)BB);
    float d20 = sqrtf(r01) + 1e-15f;
    float d21 = sqrtf(r10) + 1e-15f;
    float oa01 = r01 / (d20 * d21);
    float oa10 = r10 / (d21 * d20);
    dout[65618 + b * 4 + 0] = 0.f;
    dout[65618 + b * 4 + 1] = oa01;
    dout[65618 + b * 4 + 2] = oa10;
    dout[65618 + b * 4 + 3] = 0.f;
    sc[0] = oa01; sc[1] = oa10;
  }
  __syncthreads();
  float oa01 = sc[0], oa10 = sc[1];
  for (int f = t; f < HID; f += 256) {
    float o0 = outp[b * 1024 + f];
    float o1 = outp[b * 1024 + 512 + f];
    uv[b * HID + f] = oa10 * o1 + oa01 * o0;           // u
    uv[BB * HID + b * HID + f] = o0 + o1;              // v
  }
}

// ---------------------------------------------------------------------------
// Kernel G2: xm = 0.5*(u.Wrel3 + v.Wroot3) + brel3
// ---------------------------------------------------------------------------
__global__ __launch_bounds__(256) void conv3_xm(
    const float* __restrict__ uv, const float* __restrict__ Wrel3,
    const float* __restrict__ Wroot3, const float* __restrict__ brel3,
    float* __restrict__ xm) {
  __shared__ float us[HID], vs[HID];
  __shared__ float red[4][64];
  int b = blockIdx.x >> 3;
  int fc = blockIdx.x & 7;
  int t = threadIdx.x;
  for (int i = t; i < HID; i += 256) {
    us[i] = uv[b * HID + i];
    vs[i] = uv[BB * HID + b * HID + i];
  }
  __syncthreads();
  int f = fc * 64 + (t & 63);
  int kq = t >> 6;
  float acc = 0.f;
#pragma unroll 8
  for (int k = kq * 128; k < kq * 128 + 128; ++k)
    acc += us[k] * Wrel3[k * HID + f] + vs[k] * Wroot3[k * HID + f];
  red[kq][t & 63] = acc;
  __syncthreads();
  if (kq == 0) {
    float v2 = red[0][t] + red[1][t] + red[2][t] + red[3][t];
    xm[b * HID + f] = 0.5f * v2 + brel3[f];
  }
}

// ---------------------------------------------------------------------------
// Kernel G3: h2 = relu(xm.Wlin1 + blin1)
// ---------------------------------------------------------------------------
__global__ __launch_bounds__(256) void lin1_h2(
    const float* __restrict__ xm, const float* __restrict__ Wlin1,
    const float* __restrict__ blin1, float* __restrict__ h2) {
  __shared__ float xs[HID];
  __shared__ float red[4][64];
  int b = blockIdx.x >> 3;
  int fc = blockIdx.x & 7;
  int t = threadIdx.x;
  for (int i = t; i < HID; i += 256) xs[i] = xm[b * HID + i];
  __syncthreads();
  int f = fc * 64 + (t & 63);
  int kq = t >> 6;
  float acc = 0.f;
#pragma unroll 8
  for (int k = kq * 128; k < kq * 128 + 128; ++k)
    acc += xs[k] * Wlin1[k * HID + f];
  red[kq][t & 63] = acc;
  __syncthreads();
  if (kq == 0) {
    float v2 = red[0][t] + red[1][t] + red[2][t] + red[3][t] + blin1[f];
    h2[b * HID + f] = fmaxf(v2, 0.f);
  }
}

// ---------------------------------------------------------------------------
// Kernel G4: logits + log_softmax
// ---------------------------------------------------------------------------
__global__ __launch_bounds__(256) void head(
    const float* __restrict__ h2, const float* __restrict__ Wlin2,
    const float* __restrict__ blin2, float* __restrict__ dout) {
  __shared__ float hs[HID];
  __shared__ float lg[16];
  __shared__ float lse;
  int b = blockIdx.x, t = threadIdx.x;
  for (int i = t; i < HID; i += 256) hs[i] = h2[b * HID + i];
  __syncthreads();
  int wave = t >> 6, lane = t & 63;
  for (int o = wave; o < OUTC; o += 4) {
    float acc = 0.f;
    for (int k = lane; k < HID; k += 64)
      acc += hs[k] * Wlin2[k * OUTC + o];
#pragma unroll
    for (int off = 32; off; off >>= 1) acc += __shfl_down(acc, off, 64);
    if (lane == 0) lg[o] = acc + blin2[o];
  }
  __syncthreads();
  if (t == 0) {
    float m = lg[0];
    for (int o = 1; o < OUTC; ++o) m = fmaxf(m, lg[o]);
    float se = 0.f;
    for (int o = 0; o < OUTC; ++o) se += expf(lg[o] - m);
    lse = m + logf(se);
  }
  __syncthreads();
  if (t < OUTC) dout[b * OUTC + t] = lg[t] - lse;
}

// ---------------------------------------------------------------------------
// Launcher
// ---------------------------------------------------------------------------
extern "C" void kernel_launch(void* const* d_in, const int* in_sizes, int n_in,
                              void* d_out, int out_size, void* d_ws, size_t ws_size,
                              hipStream_t stream) {
  const float* x      = (const float*)d_in[0];
  const int*   ei     = (const int*)d_in[1];
  const float* ew     = (const float*)d_in[3];
  const float* Wrel1  = (const float*)d_in[4];
  const float* brel1  = (const float*)d_in[5];
  const float* Wroot1 = (const float*)d_in[6];
  const float* Wpool  = (const float*)d_in[7];
  const float* bpool  = (const float*)d_in[8];
  const float* Wrel3  = (const float*)d_in[9];
  const float* brel3  = (const float*)d_in[10];
  const float* Wroot3 = (const float*)d_in[11];
  const float* Wlin1  = (const float*)d_in[12];
  const float* blin1  = (const float*)d_in[13];
  const float* Wlin2  = (const float*)d_in[14];
  const float* blin2  = (const float*)d_in[15];
  float* out = (float*)d_out;
  float* ws  = (float*)d_ws;

  // workspace layout (float units)
  float* dw    = ws;                        // [0, 32768)
  float* outp  = dw + 32768;                // [32768, 40960)
  float* oadj  = outp + 8192;               // [40960, 40992)
  float* ssacc = oadj + 32;                 // [40992, 41024)
  float* mden  = ssacc + 32;                // [41024, 41032)
  int*   deg   = (int*)(mden + 8);          // [41032, 73800)  zero-region end
  int*   off   = deg + 32768;               // [73800, 106568)
  ushort* Ab   = (ushort*)(ws + 106568);    // 32768x256 bf16 = 4194304 f  [106568, 4300872)
  ushort* Bb   = (ushort*)(ws + 4300872);   // 512x256 bf16 = 65536 f      [4300872, 4366408)
  ushort* hbf  = (ushort*)(ws + 4366408);   // 32768x512 bf16 = 8388608 f  [4366408, 12755016)
  // aliases (lifetimes by stream order):
  int*   ebs   = (int*)(ws + 4366408);      // inside h region; dead before gemm writes h
  float* ebw   = ws + 4890696;              // inside h region
  float* s     = ws + 106568;               // overlays Ab; Ab dead after gemm
  float* uv    = (float*)deg;               // deg dead after gather_agg
  float* xm    = (float*)off;               // off dead after gather_agg
  float* h2    = (float*)off + 4096;

  const int* src = ei;
  const int* dst = ei + BE;

  hipMemsetAsync(ws, 0, (size_t)73800 * sizeof(float), stream);
  hipMemsetAsync(out + 80, 0, 2 * sizeof(float), stream);

  edge_count <<<BE / 256, 256, 0, stream>>>(src, dst, ew, deg, dw);
  scan_kernel<<<1, 1024, 0, stream>>>(deg, off);
  edge_bucket<<<BE / 256, 256, 0, stream>>>(src, dst, ew, off, ebs, ebw);
  gather_agg <<<BN / 4, 256, 0, stream>>>(off, deg, ebs, ebw, x, Ab);
  cast_x     <<<4096, 256, 0, stream>>>(x, Ab);
  cast_w     <<<512, 256, 0, stream>>>(Wrel1, Wroot1, Bb);
  gemm_mfma  <<<1024, 256, 0, stream>>>(Ab, Bb, brel1, hbf);
  pool_softmax<<<BN / 4, 256, 0, stream>>>(hbf, Wpool, bpool, s, out + 82);
  edge_pass2 <<<BB * 64, 256, 0, stream>>>(src, dst, ew, s, oadj);
  node_acc   <<<BN / 256, 256, 0, stream>>>(hbf, s, dw, outp, ssacc, mden);
  finalize_a <<<BB, 256, 0, stream>>>(outp, oadj, ssacc, mden, uv, out);
  conv3_xm   <<<BB * 8, 256, 0, stream>>>(uv, Wrel3, Wroot3, brel3, xm);
  lin1_h2    <<<BB * 8, 256, 0, stream>>>(xm, Wlin1, blin1, h2);
  head       <<<BB, 256, 0, stream>>>(h2, Wlin2, blin2, out);
}

// Round 5
// 321.310 us; speedup vs baseline: 2.0506x; 1.1565x over previous
//
#include <hip/hip_runtime.h>
#include <hip/hip_bf16.h>

// Problem constants
#define BB 8
#define NN 4096
#define EE 65536            // edges per graph
#define BE (BB*EE)          // 524288 total edges
#define BN (BB*NN)          // 32768 total nodes
#define INF 128
#define HID 512
#define CC 2
#define OUTC 10

typedef __bf16 bf16x8_t __attribute__((ext_vector_type(8)));
typedef float  f32x4_t  __attribute__((ext_vector_type(4)));

__device__ __forceinline__ ushort f2bf(float f) {
  union { float f; unsigned u; } v; v.f = f;
  unsigned r = v.u + 0x7FFFu + ((v.u >> 16) & 1u);   // RNE
  return (ushort)(r >> 16);
}
__device__ __forceinline__ float bf2f(ushort s) {
  union { unsigned u; float f; } v; v.u = ((unsigned)s) << 16;
  return v.f;
}

// ---------------------------------------------------------------------------
// Kernel A1: degree histogram by dst + weighted out-degree dw[src] += w
// ---------------------------------------------------------------------------
__global__ __launch_bounds__(256) void edge_count(
    const int* __restrict__ src, const int* __restrict__ dst,
    const float* __restrict__ ew, int* __restrict__ deg,
    float* __restrict__ dw) {
  int e = blockIdx.x * 256 + threadIdx.x;
  if (e >= BE) return;
  atomicAdd(&deg[dst[e]], 1);
  atomicAdd(&dw[src[e]], ew[e]);
}

// ---------------------------------------------------------------------------
// Kernel A2: exclusive prefix sum of deg[0..32767] -> off.
// ---------------------------------------------------------------------------
__global__ __launch_bounds__(1024) void scan_kernel(
    const int* __restrict__ deg, int* __restrict__ off) {
  __shared__ int part[1024];
  int t = threadIdx.x;
  int local[32];
  int s = 0;
#pragma unroll
  for (int i = 0; i < 32; ++i) { local[i] = s; s += deg[t * 32 + i]; }
  part[t] = s;
  __syncthreads();
  for (int o = 1; o < 1024; o <<= 1) {
    int v = (t >= o) ? part[t - o] : 0;
    __syncthreads();
    part[t] += v;
    __syncthreads();
  }
  int base = (t == 0) ? 0 : part[t - 1];
#pragma unroll
  for (int i = 0; i < 32; ++i) off[t * 32 + i] = base + local[i];
}

// ---------------------------------------------------------------------------
// Kernel A3: bucket edges by dst. off becomes inclusive bucket ends.
// ---------------------------------------------------------------------------
__global__ __launch_bounds__(256) void edge_bucket(
    const int* __restrict__ src, const int* __restrict__ dst,
    const float* __restrict__ ew, int* __restrict__ off,
    int* __restrict__ ebs, float* __restrict__ ebw) {
  int e = blockIdx.x * 256 + threadIdx.x;
  if (e >= BE) return;
  int d = dst[e];
  int p = atomicAdd(&off[d], 1);
  ebs[p] = src[e];
  ebw[p] = ew[e];
}

// ---------------------------------------------------------------------------
// Kernel A4: gather  A[n, 0:128] = bf16( sum_{e: dst=n} w_e * x[src_e,:] )
// ---------------------------------------------------------------------------
__global__ __launch_bounds__(256) void gather_agg(
    const int* __restrict__ off, const int* __restrict__ deg,
    const int* __restrict__ ebs, const float* __restrict__ ebw,
    const float* __restrict__ x, ushort* __restrict__ Ab) {
  int n = blockIdx.x * 4 + (threadIdx.x >> 6);
  int lane = threadIdx.x & 63;
  int end = off[n];
  int beg = end - deg[n];
  float ax = 0.f, ay = 0.f;
  int i = beg;
  for (; i + 1 < end; i += 2) {
    int s0 = ebs[i], s1 = ebs[i + 1];
    float w0 = ebw[i], w1 = ebw[i + 1];
    float2 v0 = *(const float2*)&x[(size_t)s0 * INF + lane * 2];
    float2 v1 = *(const float2*)&x[(size_t)s1 * INF + lane * 2];
    ax += w0 * v0.x + w1 * v1.x;
    ay += w0 * v0.y + w1 * v1.y;
  }
  if (i < end) {
    int s0 = ebs[i];
    float w0 = ebw[i];
    float2 v0 = *(const float2*)&x[(size_t)s0 * INF + lane * 2];
    ax += w0 * v0.x;
    ay += w0 * v0.y;
  }
  ushort2 o; o.x = f2bf(ax); o.y = f2bf(ay);
  *(ushort2*)&Ab[(size_t)n * 256 + lane * 2] = o;
}

// ---------------------------------------------------------------------------
// Kernel A5: cast x -> A[:, 128:256] bf16.  One float4 per thread.
// ---------------------------------------------------------------------------
__global__ __launch_bounds__(256) void cast_x(
    const float* __restrict__ x, ushort* __restrict__ Ab) {
  int g = blockIdx.x * 256 + threadIdx.x;        // 0..1048575
  float4 v = *(const float4*)&x[(size_t)g * 4];
  int m = g >> 5;
  int kin = (g & 31) * 4;
  ushort4 o;
  o.x = f2bf(v.x); o.y = f2bf(v.y); o.z = f2bf(v.z); o.w = f2bf(v.w);
  *(ushort4*)&Ab[(size_t)m * 256 + 128 + kin] = o;
}

// ---------------------------------------------------------------------------
// Kernel A6: Bb[n][k] = bf16 of [Wrel1;Wroot1][k][n]  (pre-transposed weights)
// ---------------------------------------------------------------------------
__global__ __launch_bounds__(256) void cast_w(
    const float* __restrict__ Wrel, const float* __restrict__ Wroot,
    ushort* __restrict__ Bb) {
  int g = blockIdx.x * 256 + threadIdx.x;        // 0..131071
  int n = g & 511, k = g >> 9;
  float w = (k < 128) ? Wrel[k * 512 + n] : Wroot[(k - 128) * 512 + n];
  Bb[n * 256 + k] = f2bf(w);
}

// ---------------------------------------------------------------------------
// Kernel C: MFMA GEMM  h = relu(A(32768x256) @ B(256x512) + b), bf16 in/out.
// 128x128 tile, 4 waves, 16x16x32 bf16 MFMA, BK=32. XCD-swizzled grid:
// blk&7 -> XCD; each XCD owns 32 row-tiles x all 4 col-tiles so the A rows
// (2 MB bf16) stay L2-resident across their 4 column blocks.
// ---------------------------------------------------------------------------
#define LDA 40
__global__ __launch_bounds__(256) void gemm_mfma(
    const ushort* __restrict__ Ab, const ushort* __restrict__ Bb,
    const float* __restrict__ brel, ushort* __restrict__ hw) {
  __shared__ ushort As[128 * LDA];
  __shared__ ushort Bs[128 * LDA];
  int tid = threadIdx.x;
  int blk = blockIdx.x;
  int xcd = blk & 7;
  int idx = blk >> 3;              // 0..127
  int by = xcd * 32 + (idx & 31);  // 0..255
  int bx = idx >> 5;               // 0..3
  int m0 = by * 128, n0 = bx * 128;
  int wave = tid >> 6, lane = tid & 63;
  int wm = (wave >> 1) * 64, wn = (wave & 1) * 64;
  int l16 = lane & 15, quad = lane >> 4;

  f32x4_t acc[4][4];
#pragma unroll
  for (int i = 0; i < 4; ++i)
#pragma unroll
    for (int j = 0; j < 4; ++j) acc[i][j] = (f32x4_t){0.f, 0.f, 0.f, 0.f};

  int r0 = tid >> 2,          k0 = (tid & 3) * 8;
  int r1 = (tid + 256) >> 2,  k1 = (tid & 3) * 8;

  int aoff[4], boff[4];
#pragma unroll
  for (int i = 0; i < 4; ++i) {
    aoff[i] = (wm + i * 16 + l16) * LDA + quad * 8;
    boff[i] = (wn + i * 16 + l16) * LDA + quad * 8;
  }

  for (int kc = 0; kc < 256; kc += 32) {
    *(uint4*)&As[r0 * LDA + k0] = *(const uint4*)&Ab[(size_t)(m0 + r0) * 256 + kc + k0];
    *(uint4*)&As[r1 * LDA + k1] = *(const uint4*)&Ab[(size_t)(m0 + r1) * 256 + kc + k1];
    *(uint4*)&Bs[r0 * LDA + k0] = *(const uint4*)&Bb[(size_t)(n0 + r0) * 256 + kc + k0];
    *(uint4*)&Bs[r1 * LDA + k1] = *(const uint4*)&Bb[(size_t)(n0 + r1) * 256 + kc + k1];
    __syncthreads();
    bf16x8_t af[4], bf[4];
#pragma unroll
    for (int i = 0; i < 4; ++i) {
      af[i] = *(const bf16x8_t*)&As[aoff[i]];
      bf[i] = *(const bf16x8_t*)&Bs[boff[i]];
    }
#pragma unroll
    for (int mt = 0; mt < 4; ++mt)
#pragma unroll
      for (int nt = 0; nt < 4; ++nt)
        acc[mt][nt] = __builtin_amdgcn_mfma_f32_16x16x32_bf16(af[mt], bf[nt], acc[mt][nt], 0, 0, 0);
    __syncthreads();
  }

#pragma unroll
  for (int nt = 0; nt < 4; ++nt) {
    int col = n0 + wn + nt * 16 + l16;
    float bias = brel[col];
#pragma unroll
    for (int mt = 0; mt < 4; ++mt) {
      int rowb = m0 + wm + mt * 16 + quad * 4;
#pragma unroll
      for (int r = 0; r < 4; ++r) {
        float v = fmaxf(acc[mt][nt][r] + bias, 0.f);
        hw[(size_t)(rowb + r) * 512 + col] = f2bf(v);
      }
    }
  }
}

// ---------------------------------------------------------------------------
// Kernel D: s_logits = h @ W_pool + b_pool ; s = softmax(s_logits). h is bf16.
// ---------------------------------------------------------------------------
__global__ __launch_bounds__(256) void pool_softmax(
    const ushort* __restrict__ hw, const float* __restrict__ Wp,
    const float* __restrict__ bp, float* __restrict__ s,
    float* __restrict__ slog) {
  __shared__ float wp0[HID], wp1[HID];
  int tid = threadIdx.x;
  for (int i = tid; i < HID; i += 256) {
    wp0[i] = Wp[i * 2];
    wp1[i] = Wp[i * 2 + 1];
  }
  __syncthreads();
  int wave = tid >> 6, lane = tid & 63;
  int n = blockIdx.x * 4 + wave;
  float acc0 = 0.f, acc1 = 0.f;
#pragma unroll
  for (int j = 0; j < 8; ++j) {
    int f = lane + j * 64;
    float hv = bf2f(hw[(size_t)n * HID + f]);
    acc0 += hv * wp0[f];
    acc1 += hv * wp1[f];
  }
#pragma unroll
  for (int off = 32; off; off >>= 1) {
    acc0 += __shfl_down(acc0, off, 64);
    acc1 += __shfl_down(acc1, off, 64);
  }
  if (lane == 0) {
    float l0 = acc0 + bp[0], l1 = acc1 + bp[1];
    slog[n * 2] = l0;
    slog[n * 2 + 1] = l1;
    float m = fmaxf(l0, l1);
    float e0 = expf(l0 - m), e1 = expf(l1 - m);
    float inv = 1.f / (e0 + e1);
    s[n * 2] = e0 * inv;
    s[n * 2 + 1] = e1 * inv;
  }
}

// ---------------------------------------------------------------------------
// Kernel E: out_adj_raw[b,i,j] = sum_e w_e * s[src,i] * s[dst,j]
// ---------------------------------------------------------------------------
__global__ __launch_bounds__(256) void edge_pass2(
    const int* __restrict__ src, const int* __restrict__ dst,
    const float* __restrict__ ew, const float* __restrict__ s,
    float* __restrict__ oadj) {
  int b = blockIdx.x >> 6;
  int sub = blockIdx.x & 63;
  int base = b * EE + sub * 1024;
  float p00 = 0, p01 = 0, p10 = 0, p11 = 0;
  for (int i = threadIdx.x; i < 1024; i += 256) {
    int e = base + i;
    int r = src[e], c = dst[e];
    float w = ew[e];
    float s0r = s[r * 2], s1r = s[r * 2 + 1];
    float s0c = s[c * 2], s1c = s[c * 2 + 1];
    p00 += w * s0r * s0c; p01 += w * s0r * s1c;
    p10 += w * s1r * s0c; p11 += w * s1r * s1c;
  }
#pragma unroll
  for (int off = 32; off; off >>= 1) {
    p00 += __shfl_down(p00, off, 64);
    p01 += __shfl_down(p01, off, 64);
    p10 += __shfl_down(p10, off, 64);
    p11 += __shfl_down(p11, off, 64);
  }
  __shared__ float red[4][4];
  int wave = threadIdx.x >> 6, lane = threadIdx.x & 63;
  if (lane == 0) {
    red[wave][0] = p00; red[wave][1] = p01;
    red[wave][2] = p10; red[wave][3] = p11;
  }
  __syncthreads();
  if (threadIdx.x < 4) {
    float v = red[0][threadIdx.x] + red[1][threadIdx.x] +
              red[2][threadIdx.x] + red[3][threadIdx.x];
    atomicAdd(&oadj[b * 4 + threadIdx.x], v);
  }
}

// ---------------------------------------------------------------------------
// Kernel F: out[b,c,:] += s[n,c]*h[n,:] ; ss accumulators ; mincut_den
// ---------------------------------------------------------------------------
__global__ __launch_bounds__(256) void node_acc(
    const ushort* __restrict__ hw, const float* __restrict__ s,
    const float* __restrict__ dw, float* __restrict__ outp,
    float* __restrict__ ssacc, float* __restrict__ mden) {
  int blk = blockIdx.x;            // 128 blocks
  int b = blk >> 4;
  int n0 = blk * 256;
  int t = threadIdx.x;
  float a00 = 0, a01 = 0, a10 = 0, a11 = 0;
  float sa = 0, sb = 0, scv = 0, md = 0;
  for (int i = 0; i < 256; ++i) {
    int n = n0 + i;
    float s0 = s[n * 2], s1 = s[n * 2 + 1];
    float h0 = bf2f(hw[(size_t)n * HID + t]);
    float h1 = bf2f(hw[(size_t)n * HID + t + 256]);
    a00 += s0 * h0; a01 += s0 * h1;
    a10 += s1 * h0; a11 += s1 * h1;
    if (t == 0) {
      float dn = dw[n];
      sa += s0 * s0; sb += s0 * s1; scv += s1 * s1;
      md += dn * (s0 * s0 + s1 * s1);
    }
  }
  atomicAdd(&outp[b * 1024 + t], a00);
  atomicAdd(&outp[b * 1024 + t + 256], a01);
  atomicAdd(&outp[b * 1024 + 512 + t], a10);
  atomicAdd(&outp[b * 1024 + 512 + t + 256], a11);
  if (t == 0) {
    atomicAdd(&ssacc[b * 4 + 0], sa);
    atomicAdd(&ssacc[b * 4 + 1], sb);
    atomicAdd(&ssacc[b * 4 + 2], scv);
    atomicAdd(&mden[b], md);
  }
}

// ---------------------------------------------------------------------------
// Kernel G1: per-graph scalars + build u,v vectors.
// ---------------------------------------------------------------------------
__global__ __launch_bounds__(256) void finalize_a(
    const float* __restrict__ outp, const float* __restrict__ oadj,
    const float* __restrict__ ssacc, const float* __restrict__ mden,
    float* __restrict__ uv, float* __restrict__ dout) {
  __shared__ float sc[2];
  int b = blockIdx.x, t = threadIdx.x;
  if (t == 0) {
    float r00 = oadj[b * 4 + 0], r01 = oadj[b * 4 + 1];
    float r10 = oadj[b * 4 + 2], r11 = oadj[b * 4 + 3];
    atomicAdd(&dout[80], -((r00 + r11) / mden[b]) / (float)BB);
    float a = ssacc[b * 4 + 0], bb = ssacc[b * 4 + 1], c = ssacc[b * 4 + 2];
    float nrm = sqrtf(a * a + 2.f * bb * bb + c * c);
    float q = 0.70710678118654752f;
    float da = a / nrm - q, db = bb / nrm, dc = c / nrm - q;
    atomicAdd(&dout[81], sqrtf(da * da + 2.f * db * db + dc * dc) / (float)BB);
    float d20 = sqrtf(r01) + 1e-15f;
    float d21 = sqrtf(r10) + 1e-15f;
    float oa01 = r01 / (d20 * d21);
    float oa10 = r10 / (d21 * d20);
    dout[65618 + b * 4 + 0] = 0.f;
    dout[65618 + b * 4 + 1] = oa01;
    dout[65618 + b * 4 + 2] = oa10;
    dout[65618 + b * 4 + 3] = 0.f;
    sc[0] = oa01; sc[1] = oa10;
  }
  __syncthreads();
  float oa01 = sc[0], oa10 = sc[1];
  for (int f = t; f < HID; f += 256) {
    float o0 = outp[b * 1024 + f];
    float o1 = outp[b * 1024 + 512 + f];
    uv[b * HID + f] = oa10 * o1 + oa01 * o0;           // u
    uv[BB * HID + b * HID + f] = o0 + o1;              // v
  }
}

// ---------------------------------------------------------------------------
// Kernel G2: conv3 split-K partials. Grid 128 = kc(16) x fc(8); each 4B
// weight load is reused across all 8 graphs; 16 independent loads/thread.
// xmacc[b*512+f] += sum_k u[b][k]*Wrel3[k][f] + v[b][k]*Wroot3[k][f]
// ---------------------------------------------------------------------------
__global__ __launch_bounds__(256) void conv3_part(
    const float* __restrict__ uv, const float* __restrict__ Wrel3,
    const float* __restrict__ Wroot3, float* __restrict__ xmacc) {
  __shared__ float us[8][32], vs[8][32];
  __shared__ float red[4][64][8];
  int blk = blockIdx.x;
  int fc = blk & 7, kc = blk >> 3;
  int t = threadIdx.x;
  {
    int b = t >> 5, k = t & 31;
    us[b][k] = uv[b * HID + kc * 32 + k];
    vs[b][k] = uv[BB * HID + b * HID + kc * 32 + k];
  }
  __syncthreads();
  int f = fc * 64 + (t & 63);
  int ks = t >> 6;                 // 0..3
  float acc[8] = {0, 0, 0, 0, 0, 0, 0, 0};
#pragma unroll
  for (int j = 0; j < 8; ++j) {
    int kl = ks * 8 + j;           // 0..31
    int k = kc * 32 + kl;
    float wr = Wrel3[k * HID + f];
    float wo = Wroot3[k * HID + f];
#pragma unroll
    for (int b = 0; b < 8; ++b)
      acc[b] += us[b][kl] * wr + vs[b][kl] * wo;
  }
#pragma unroll
  for (int b = 0; b < 8; ++b) red[ks][t & 63][b] = acc[b];
  __syncthreads();
  if (ks == 0) {
    int fl = t & 63;
#pragma unroll
    for (int b = 0; b < 8; ++b) {
      float v = red[0][fl][b] + red[1][fl][b] + red[2][fl][b] + red[3][fl][b];
      atomicAdd(&xmacc[b * HID + f], v);
    }
  }
}

// ---------------------------------------------------------------------------
// Kernel G3: lin1 split-K partials; xm = 0.5*xmacc + brel3 applied at staging.
// h2acc[b*512+f] += sum_k xm[b][k]*Wlin1[k][f]
// ---------------------------------------------------------------------------
__global__ __launch_bounds__(256) void lin1_part(
    const float* __restrict__ xmacc, const float* __restrict__ brel3,
    const float* __restrict__ Wlin1, float* __restrict__ h2acc) {
  __shared__ float xs[8][32];
  __shared__ float red[4][64][8];
  int blk = blockIdx.x;
  int fc = blk & 7, kc = blk >> 3;
  int t = threadIdx.x;
  {
    int b = t >> 5, k = t & 31;
    xs[b][k] = 0.5f * xmacc[b * HID + kc * 32 + k] + brel3[kc * 32 + k];
  }
  __syncthreads();
  int f = fc * 64 + (t & 63);
  int ks = t >> 6;
  float acc[8] = {0, 0, 0, 0, 0, 0, 0, 0};
#pragma unroll
  for (int j = 0; j < 8; ++j) {
    int kl = ks * 8 + j;
    int k = kc * 32 + kl;
    float w = Wlin1[k * HID + f];
#pragma unroll
    for (int b = 0; b < 8; ++b)
      acc[b] += xs[b][kl] * w;
  }
#pragma unroll
  for (int b = 0; b < 8; ++b) red[ks][t & 63][b] = acc[b];
  __syncthreads();
  if (ks == 0) {
    int fl = t & 63;
#pragma unroll
    for (int b = 0; b < 8; ++b) {
      float v = red[0][fl][b] + red[1][fl][b] + red[2][fl][b] + red[3][fl][b];
      atomicAdd(&h2acc[b * HID + f], v);
    }
  }
}

// ---------------------------------------------------------------------------
// Kernel G4: logits + log_softmax; h2 = relu(h2acc + blin1) at staging.
// ---------------------------------------------------------------------------
__global__ __launch_bounds__(256) void head(
    const float* __restrict__ h2acc, const float* __restrict__ blin1,
    const float* __restrict__ Wlin2, const float* __restrict__ blin2,
    float* __restrict__ dout) {
  __shared__ float hs[HID];
  __shared__ float lg[16];
  __shared__ float lse;
  int b = blockIdx.x, t = threadIdx.x;
  for (int i = t; i < HID; i += 256)
    hs[i] = fmaxf(h2acc[b * HID + i] + blin1[i], 0.f);
  __syncthreads();
  int wave = t >> 6, lane = t & 63;
  for (int o = wave; o < OUTC; o += 4) {
    float acc = 0.f;
    for (int k = lane; k < HID; k += 64)
      acc += hs[k] * Wlin2[k * OUTC + o];
#pragma unroll
    for (int off = 32; off; off >>= 1) acc += __shfl_down(acc, off, 64);
    if (lane == 0) lg[o] = acc + blin2[o];
  }
  __syncthreads();
  if (t == 0) {
    float m = lg[0];
    for (int o = 1; o < OUTC; ++o) m = fmaxf(m, lg[o]);
    float se = 0.f;
    for (int o = 0; o < OUTC; ++o) se += expf(lg[o] - m);
    lse = m + logf(se);
  }
  __syncthreads();
  if (t < OUTC) dout[b * OUTC + t] = lg[t] - lse;
}

// ---------------------------------------------------------------------------
// Launcher
// ---------------------------------------------------------------------------
extern "C" void kernel_launch(void* const* d_in, const int* in_sizes, int n_in,
                              void* d_out, int out_size, void* d_ws, size_t ws_size,
                              hipStream_t stream) {
  const float* x      = (const float*)d_in[0];
  const int*   ei     = (const int*)d_in[1];
  const float* ew     = (const float*)d_in[3];
  const float* Wrel1  = (const float*)d_in[4];
  const float* brel1  = (const float*)d_in[5];
  const float* Wroot1 = (const float*)d_in[6];
  const float* Wpool  = (const float*)d_in[7];
  const float* bpool  = (const float*)d_in[8];
  const float* Wrel3  = (const float*)d_in[9];
  const float* brel3  = (const float*)d_in[10];
  const float* Wroot3 = (const float*)d_in[11];
  const float* Wlin1  = (const float*)d_in[12];
  const float* blin1  = (const float*)d_in[13];
  const float* Wlin2  = (const float*)d_in[14];
  const float* blin2  = (const float*)d_in[15];
  float* out = (float*)d_out;
  float* ws  = (float*)d_ws;

  // workspace layout (float units)
  float* dw    = ws;                        // [0, 32768)
  float* outp  = dw + 32768;                // [32768, 40960)
  float* oadj  = outp + 8192;               // [40960, 40992)
  float* ssacc = oadj + 32;                 // [40992, 41024)
  float* mden  = ssacc + 32;                // [41024, 41032)
  int*   deg   = (int*)(mden + 8);          // [41032, 73800)  zero-region end
  int*   off   = deg + 32768;               // [73800, 106568)
  ushort* Ab   = (ushort*)(ws + 106568);    // 32768x256 bf16  [106568, 4300872)
  ushort* Bb   = (ushort*)(ws + 4300872);   // 512x256 bf16    [4300872, 4366408)
  ushort* hbf  = (ushort*)(ws + 4366408);   // 32768x512 bf16  [4366408, 12755016)
  float* xmacc = ws + 12755016;             // 4096            [12755016, 12759112)
  float* h2acc = xmacc + 4096;              // 4096            [12759112, 12763208)
  // aliases (lifetimes by stream order):
  int*   ebs   = (int*)(ws + 4366408);      // inside h region; dead before gemm writes h
  float* ebw   = ws + 4890696;              // inside h region
  float* s     = ws + 106568;               // overlays Ab; Ab dead after gemm
  float* uv    = (float*)deg;               // deg dead after gather_agg

  const int* src = ei;
  const int* dst = ei + BE;

  hipMemsetAsync(ws, 0, (size_t)73800 * sizeof(float), stream);
  hipMemsetAsync(xmacc, 0, (size_t)8192 * sizeof(float), stream);
  hipMemsetAsync(out + 80, 0, 2 * sizeof(float), stream);

  edge_count <<<BE / 256, 256, 0, stream>>>(src, dst, ew, deg, dw);
  scan_kernel<<<1, 1024, 0, stream>>>(deg, off);
  edge_bucket<<<BE / 256, 256, 0, stream>>>(src, dst, ew, off, ebs, ebw);
  gather_agg <<<BN / 4, 256, 0, stream>>>(off, deg, ebs, ebw, x, Ab);
  cast_x     <<<4096, 256, 0, stream>>>(x, Ab);
  cast_w     <<<512, 256, 0, stream>>>(Wrel1, Wroot1, Bb);
  gemm_mfma  <<<1024, 256, 0, stream>>>(Ab, Bb, brel1, hbf);
  pool_softmax<<<BN / 4, 256, 0, stream>>>(hbf, Wpool, bpool, s, out + 82);
  edge_pass2 <<<BB * 64, 256, 0, stream>>>(src, dst, ew, s, oadj);
  node_acc   <<<BN / 256, 256, 0, stream>>>(hbf, s, dw, outp, ssacc, mden);
  finalize_a <<<BB, 256, 0, stream>>>(outp, oadj, ssacc, mden, uv, out);
  conv3_part <<<128, 256, 0, stream>>>(uv, Wrel3, Wroot3, xmacc);
  lin1_part  <<<128, 256, 0, stream>>>(xmacc, brel3, Wlin1, h2acc);
  head       <<<BB, 256, 0, stream>>>(h2acc, blin1, Wlin2, blin2, out);
}

// Round 6
// 311.228 us; speedup vs baseline: 2.1170x; 1.0324x over previous
//
#include <hip/hip_runtime.h>
#include <hip/hip_bf16.h>

// Problem constants
#define BB 8
#define NN 4096
#define EE 65536            // edges per graph
#define BE (BB*EE)          // 524288 total edges
#define BN (BB*NN)          // 32768 total nodes
#define INF 128
#define HID 512
#define CC 2
#define OUTC 10

typedef __bf16 bf16x8_t __attribute__((ext_vector_type(8)));
typedef float  f32x4_t  __attribute__((ext_vector_type(4)));

__device__ __forceinline__ ushort f2bf(float f) {
  union { float f; unsigned u; } v; v.f = f;
  unsigned r = v.u + 0x7FFFu + ((v.u >> 16) & 1u);   // RNE
  return (ushort)(r >> 16);
}
__device__ __forceinline__ float bf2f(ushort s) {
  union { unsigned u; float f; } v; v.u = ((unsigned)s) << 16;
  return v.f;
}

// ---------------------------------------------------------------------------
// Kernel A1: owner-computes degree histogram. 64 blocks = (graph b = blk&7,
// dst-range r = blk>>3, 512 nodes). Block scans ALL graph-b edges (int4),
// LDS-counts only its own dst range, plain-stores deg. ZERO global atomics.
// blk&7 = graph keeps each graph's dst array on one XCD's L2 (8 readers).
// ---------------------------------------------------------------------------
__global__ __launch_bounds__(256) void edge_count(
    const int* __restrict__ dst, int* __restrict__ deg) {
  __shared__ int cnt[512];
  int blk = blockIdx.x;
  int b = blk & 7, r = blk >> 3;
  int base = b * NN + r * 512;
  int t = threadIdx.x;
  cnt[t] = 0; cnt[t + 256] = 0;
  __syncthreads();
  const int4* d4 = (const int4*)(dst + (size_t)b * EE);
  for (int i = t; i < EE / 4; i += 256) {
    int4 v = d4[i];
    int a0 = v.x - base; if ((unsigned)a0 < 512u) atomicAdd(&cnt[a0], 1);
    int a1 = v.y - base; if ((unsigned)a1 < 512u) atomicAdd(&cnt[a1], 1);
    int a2 = v.z - base; if ((unsigned)a2 < 512u) atomicAdd(&cnt[a2], 1);
    int a3 = v.w - base; if ((unsigned)a3 < 512u) atomicAdd(&cnt[a3], 1);
  }
  __syncthreads();
  deg[base + t] = cnt[t];
  deg[base + t + 256] = cnt[t + 256];
}

// ---------------------------------------------------------------------------
// Kernel A2: exclusive prefix sum of deg[0..32767] -> off (pristine starts).
// ---------------------------------------------------------------------------
__global__ __launch_bounds__(1024) void scan_kernel(
    const int* __restrict__ deg, int* __restrict__ off) {
  __shared__ int part[1024];
  int t = threadIdx.x;
  int local[32];
  int s = 0;
#pragma unroll
  for (int i = 0; i < 32; ++i) { local[i] = s; s += deg[t * 32 + i]; }
  part[t] = s;
  __syncthreads();
  for (int o = 1; o < 1024; o <<= 1) {
    int v = (t >= o) ? part[t - o] : 0;
    __syncthreads();
    part[t] += v;
    __syncthreads();
  }
  int base = (t == 0) ? 0 : part[t - 1];
#pragma unroll
  for (int i = 0; i < 32; ++i) off[t * 32 + i] = base + local[i];
}

// ---------------------------------------------------------------------------
// Kernel A3: owner-computes bucketing. Same 64-block partition as edge_count;
// LDS cursors seeded from off (NOT mutated); each block's writes land in an
// exclusively-owned contiguous region (scan is node-ordered). No atomics.
// ---------------------------------------------------------------------------
__global__ __launch_bounds__(256) void edge_bucket(
    const int* __restrict__ src, const int* __restrict__ dst,
    const float* __restrict__ ew, const int* __restrict__ off,
    int* __restrict__ ebs, float* __restrict__ ebw) {
  __shared__ int cur[512];
  int blk = blockIdx.x;
  int b = blk & 7, r = blk >> 3;
  int base = b * NN + r * 512;
  int t = threadIdx.x;
  cur[t] = off[base + t];
  cur[t + 256] = off[base + t + 256];
  __syncthreads();
  size_t e0 = (size_t)b * EE;
  const int4*   s4 = (const int4*)(src + e0);
  const int4*   d4 = (const int4*)(dst + e0);
  const float4* w4 = (const float4*)(ew + e0);
  for (int i = t; i < EE / 4; i += 256) {
    int4 sv = s4[i]; int4 dv = d4[i]; float4 wv = w4[i];
    int a;
    a = dv.x - base; if ((unsigned)a < 512u) { int p = atomicAdd(&cur[a], 1); ebs[p] = sv.x; ebw[p] = wv.x; }
    a = dv.y - base; if ((unsigned)a < 512u) { int p = atomicAdd(&cur[a], 1); ebs[p] = sv.y; ebw[p] = wv.y; }
    a = dv.z - base; if ((unsigned)a < 512u) { int p = atomicAdd(&cur[a], 1); ebs[p] = sv.z; ebw[p] = wv.z; }
    a = dv.w - base; if ((unsigned)a < 512u) { int p = atomicAdd(&cur[a], 1); ebs[p] = sv.w; ebw[p] = wv.w; }
  }
}

// ---------------------------------------------------------------------------
// Kernel A4: gather  A[n, 0:128] = bf16( sum_{e: dst=n} w_e * x[src_e,:] )
// ---------------------------------------------------------------------------
__global__ __launch_bounds__(256) void gather_agg(
    const int* __restrict__ off, const int* __restrict__ deg,
    const int* __restrict__ ebs, const float* __restrict__ ebw,
    const float* __restrict__ x, ushort* __restrict__ Ab) {
  int n = blockIdx.x * 4 + (threadIdx.x >> 6);
  int lane = threadIdx.x & 63;
  int beg = off[n];
  int end = beg + deg[n];
  float ax = 0.f, ay = 0.f;
  int i = beg;
  for (; i + 1 < end; i += 2) {
    int s0 = ebs[i], s1 = ebs[i + 1];
    float w0 = ebw[i], w1 = ebw[i + 1];
    float2 v0 = *(const float2*)&x[(size_t)s0 * INF + lane * 2];
    float2 v1 = *(const float2*)&x[(size_t)s1 * INF + lane * 2];
    ax += w0 * v0.x + w1 * v1.x;
    ay += w0 * v0.y + w1 * v1.y;
  }
  if (i < end) {
    int s0 = ebs[i];
    float w0 = ebw[i];
    float2 v0 = *(const float2*)&x[(size_t)s0 * INF + lane * 2];
    ax += w0 * v0.x;
    ay += w0 * v0.y;
  }
  ushort2 o; o.x = f2bf(ax); o.y = f2bf(ay);
  *(ushort2*)&Ab[(size_t)n * 256 + lane * 2] = o;
}

// ---------------------------------------------------------------------------
// Kernel A5: cast x -> A[:, 128:256] bf16.  One float4 per thread.
// ---------------------------------------------------------------------------
__global__ __launch_bounds__(256) void cast_x(
    const float* __restrict__ x, ushort* __restrict__ Ab) {
  int g = blockIdx.x * 256 + threadIdx.x;        // 0..1048575
  float4 v = *(const float4*)&x[(size_t)g * 4];
  int m = g >> 5;
  int kin = (g & 31) * 4;
  ushort4 o;
  o.x = f2bf(v.x); o.y = f2bf(v.y); o.z = f2bf(v.z); o.w = f2bf(v.w);
  *(ushort4*)&Ab[(size_t)m * 256 + 128 + kin] = o;
}

// ---------------------------------------------------------------------------
// Kernel A6: Bb[n][k] = bf16 of [Wrel1;Wroot1][k][n]  (pre-transposed weights)
// ---------------------------------------------------------------------------
__global__ __launch_bounds__(256) void cast_w(
    const float* __restrict__ Wrel, const float* __restrict__ Wroot,
    ushort* __restrict__ Bb) {
  int g = blockIdx.x * 256 + threadIdx.x;        // 0..131071
  int n = g & 511, k = g >> 9;
  float w = (k < 128) ? Wrel[k * 512 + n] : Wroot[(k - 128) * 512 + n];
  Bb[n * 256 + k] = f2bf(w);
}

// ---------------------------------------------------------------------------
// Kernel C: MFMA GEMM  h = relu(A(32768x256) @ B(256x512) + b), bf16 in/out.
// 128x128 tile, 4 waves, 16x16x32 bf16 MFMA, BK=32, XCD-swizzled grid.
// ---------------------------------------------------------------------------
#define LDA 40
__global__ __launch_bounds__(256) void gemm_mfma(
    const ushort* __restrict__ Ab, const ushort* __restrict__ Bb,
    const float* __restrict__ brel, ushort* __restrict__ hw) {
  __shared__ ushort As[128 * LDA];
  __shared__ ushort Bs[128 * LDA];
  int tid = threadIdx.x;
  int blk = blockIdx.x;
  int xcd = blk & 7;
  int idx = blk >> 3;              // 0..127
  int by = xcd * 32 + (idx & 31);  // 0..255
  int bx = idx >> 5;               // 0..3
  int m0 = by * 128, n0 = bx * 128;
  int wave = tid >> 6, lane = tid & 63;
  int wm = (wave >> 1) * 64, wn = (wave & 1) * 64;
  int l16 = lane & 15, quad = lane >> 4;

  f32x4_t acc[4][4];
#pragma unroll
  for (int i = 0; i < 4; ++i)
#pragma unroll
    for (int j = 0; j < 4; ++j) acc[i][j] = (f32x4_t){0.f, 0.f, 0.f, 0.f};

  int r0 = tid >> 2,          k0 = (tid & 3) * 8;
  int r1 = (tid + 256) >> 2,  k1 = (tid & 3) * 8;

  int aoff[4], boff[4];
#pragma unroll
  for (int i = 0; i < 4; ++i) {
    aoff[i] = (wm + i * 16 + l16) * LDA + quad * 8;
    boff[i] = (wn + i * 16 + l16) * LDA + quad * 8;
  }

  for (int kc = 0; kc < 256; kc += 32) {
    *(uint4*)&As[r0 * LDA + k0] = *(const uint4*)&Ab[(size_t)(m0 + r0) * 256 + kc + k0];
    *(uint4*)&As[r1 * LDA + k1] = *(const uint4*)&Ab[(size_t)(m0 + r1) * 256 + kc + k1];
    *(uint4*)&Bs[r0 * LDA + k0] = *(const uint4*)&Bb[(size_t)(n0 + r0) * 256 + kc + k0];
    *(uint4*)&Bs[r1 * LDA + k1] = *(const uint4*)&Bb[(size_t)(n0 + r1) * 256 + kc + k1];
    __syncthreads();
    bf16x8_t af[4], bf[4];
#pragma unroll
    for (int i = 0; i < 4; ++i) {
      af[i] = *(const bf16x8_t*)&As[aoff[i]];
      bf[i] = *(const bf16x8_t*)&Bs[boff[i]];
    }
#pragma unroll
    for (int mt = 0; mt < 4; ++mt)
#pragma unroll
      for (int nt = 0; nt < 4; ++nt)
        acc[mt][nt] = __builtin_amdgcn_mfma_f32_16x16x32_bf16(af[mt], bf[nt], acc[mt][nt], 0, 0, 0);
    __syncthreads();
  }

#pragma unroll
  for (int nt = 0; nt < 4; ++nt) {
    int col = n0 + wn + nt * 16 + l16;
    float bias = brel[col];
#pragma unroll
    for (int mt = 0; mt < 4; ++mt) {
      int rowb = m0 + wm + mt * 16 + quad * 4;
#pragma unroll
      for (int r = 0; r < 4; ++r) {
        float v = fmaxf(acc[mt][nt][r] + bias, 0.f);
        hw[(size_t)(rowb + r) * 512 + col] = f2bf(v);
      }
    }
  }
}

// ---------------------------------------------------------------------------
// Kernel D: s_logits = h @ W_pool + b_pool ; s = softmax(s_logits). h is bf16.
// ---------------------------------------------------------------------------
__global__ __launch_bounds__(256) void pool_softmax(
    const ushort* __restrict__ hw, const float* __restrict__ Wp,
    const float* __restrict__ bp, float* __restrict__ s,
    float* __restrict__ slog) {
  __shared__ float wp0[HID], wp1[HID];
  int tid = threadIdx.x;
  for (int i = tid; i < HID; i += 256) {
    wp0[i] = Wp[i * 2];
    wp1[i] = Wp[i * 2 + 1];
  }
  __syncthreads();
  int wave = tid >> 6, lane = tid & 63;
  int n = blockIdx.x * 4 + wave;
  float acc0 = 0.f, acc1 = 0.f;
#pragma unroll
  for (int j = 0; j < 8; ++j) {
    int f = lane + j * 64;
    float hv = bf2f(hw[(size_t)n * HID + f]);
    acc0 += hv * wp0[f];
    acc1 += hv * wp1[f];
  }
#pragma unroll
  for (int off = 32; off; off >>= 1) {
    acc0 += __shfl_down(acc0, off, 64);
    acc1 += __shfl_down(acc1, off, 64);
  }
  if (lane == 0) {
    float l0 = acc0 + bp[0], l1 = acc1 + bp[1];
    slog[n * 2] = l0;
    slog[n * 2 + 1] = l1;
    float m = fmaxf(l0, l1);
    float e0 = expf(l0 - m), e1 = expf(l1 - m);
    float inv = 1.f / (e0 + e1);
    s[n * 2] = e0 * inv;
    s[n * 2 + 1] = e1 * inv;
  }
}

// ---------------------------------------------------------------------------
// Kernel E: out_adj_raw[b,i,j] = sum_e w_e * s[src,i] * s[dst,j]
// + mincut_den[b] = sum_e w_e * (s0[src]^2 + s1[src]^2)   (dw folded in)
// ---------------------------------------------------------------------------
__global__ __launch_bounds__(256) void edge_pass2(
    const int* __restrict__ src, const int* __restrict__ dst,
    const float* __restrict__ ew, const float* __restrict__ s,
    float* __restrict__ oadj, float* __restrict__ mden) {
  int b = blockIdx.x >> 6;
  int sub = blockIdx.x & 63;
  int base = b * EE + sub * 1024;
  float p00 = 0, p01 = 0, p10 = 0, p11 = 0, md = 0;
  for (int i = threadIdx.x; i < 1024; i += 256) {
    int e = base + i;
    int r = src[e], c = dst[e];
    float w = ew[e];
    float s0r = s[r * 2], s1r = s[r * 2 + 1];
    float s0c = s[c * 2], s1c = s[c * 2 + 1];
    p00 += w * s0r * s0c; p01 += w * s0r * s1c;
    p10 += w * s1r * s0c; p11 += w * s1r * s1c;
    md  += w * (s0r * s0r + s1r * s1r);
  }
#pragma unroll
  for (int off = 32; off; off >>= 1) {
    p00 += __shfl_down(p00, off, 64);
    p01 += __shfl_down(p01, off, 64);
    p10 += __shfl_down(p10, off, 64);
    p11 += __shfl_down(p11, off, 64);
    md  += __shfl_down(md,  off, 64);
  }
  __shared__ float red[4][5];
  int wave = threadIdx.x >> 6, lane = threadIdx.x & 63;
  if (lane == 0) {
    red[wave][0] = p00; red[wave][1] = p01;
    red[wave][2] = p10; red[wave][3] = p11;
    red[wave][4] = md;
  }
  __syncthreads();
  if (threadIdx.x < 4) {
    float v = red[0][threadIdx.x] + red[1][threadIdx.x] +
              red[2][threadIdx.x] + red[3][threadIdx.x];
    atomicAdd(&oadj[b * 4 + threadIdx.x], v);
  } else if (threadIdx.x == 4) {
    float v = red[0][4] + red[1][4] + red[2][4] + red[3][4];
    atomicAdd(&mden[b], v);
  }
}

// ---------------------------------------------------------------------------
// Kernel F: out[b,c,:] += s[n,c]*h[n,:] ; ss accumulators
// ---------------------------------------------------------------------------
__global__ __launch_bounds__(256) void node_acc(
    const ushort* __restrict__ hw, const float* __restrict__ s,
    float* __restrict__ outp, float* __restrict__ ssacc) {
  int blk = blockIdx.x;            // 128 blocks
  int b = blk >> 4;
  int n0 = blk * 256;
  int t = threadIdx.x;
  float a00 = 0, a01 = 0, a10 = 0, a11 = 0;
  float sa = 0, sb = 0, scv = 0;
  for (int i = 0; i < 256; ++i) {
    int n = n0 + i;
    float s0 = s[n * 2], s1 = s[n * 2 + 1];
    float h0 = bf2f(hw[(size_t)n * HID + t]);
    float h1 = bf2f(hw[(size_t)n * HID + t + 256]);
    a00 += s0 * h0; a01 += s0 * h1;
    a10 += s1 * h0; a11 += s1 * h1;
    if (t == 0) {
      sa += s0 * s0; sb += s0 * s1; scv += s1 * s1;
    }
  }
  atomicAdd(&outp[b * 1024 + t], a00);
  atomicAdd(&outp[b * 1024 + t + 256], a01);
  atomicAdd(&outp[b * 1024 + 512 + t], a10);
  atomicAdd(&outp[b * 1024 + 512 + t + 256], a11);
  if (t == 0) {
    atomicAdd(&ssacc[b * 4 + 0], sa);
    atomicAdd(&ssacc[b * 4 + 1], sb);
    atomicAdd(&ssacc[b * 4 + 2], scv);
  }
}

// ---------------------------------------------------------------------------
// Kernel G1: per-graph scalars + build u,v vectors.
// ---------------------------------------------------------------------------
__global__ __launch_bounds__(256) void finalize_a(
    const float* __restrict__ outp, const float* __restrict__ oadj,
    const float* __restrict__ ssacc, const float* __restrict__ mden,
    float* __restrict__ uv, float* __restrict__ dout) {
  __shared__ float sc[2];
  int b = blockIdx.x, t = threadIdx.x;
  if (t == 0) {
    float r00 = oadj[b * 4 + 0], r01 = oadj[b * 4 + 1];
    float r10 = oadj[b * 4 + 2], r11 = oadj[b * 4 + 3];
    atomicAdd(&dout[80], -((r00 + r11) / mden[b]) / (float)BB);
    float a = ssacc[b * 4 + 0], bb = ssacc[b * 4 + 1], c = ssacc[b * 4 + 2];
    float nrm = sqrtf(a * a + 2.f * bb * bb + c * c);
    float q = 0.70710678118654752f;
    float da = a / nrm - q, db = bb / nrm, dc = c / nrm - q;
    atomicAdd(&dout[81], sqrtf(da * da + 2.f * db * db + dc * dc) / (float)BB);
    float d20 = sqrtf(r01) + 1e-15f;
    float d21 = sqrtf(r10) + 1e-15f;
    float oa01 = r01 / (d20 * d21);
    float oa10 = r10 / (d21 * d20);
    dout[65618 + b * 4 + 0] = 0.f;
    dout[65618 + b * 4 + 1] = oa01;
    dout[65618 + b * 4 + 2] = oa10;
    dout[65618 + b * 4 + 3] = 0.f;
    sc[0] = oa01; sc[1] = oa10;
  }
  __syncthreads();
  float oa01 = sc[0], oa10 = sc[1];
  for (int f = t; f < HID; f += 256) {
    float o0 = outp[b * 1024 + f];
    float o1 = outp[b * 1024 + 512 + f];
    uv[b * HID + f] = oa10 * o1 + oa01 * o0;           // u
    uv[BB * HID + b * HID + f] = o0 + o1;              // v
  }
}

// ---------------------------------------------------------------------------
// Kernel G2: conv3 split-K partials. Grid 128 = kc(16) x fc(8).
// ---------------------------------------------------------------------------
__global__ __launch_bounds__(256) void conv3_part(
    const float* __restrict__ uv, const float* __restrict__ Wrel3,
    const float* __restrict__ Wroot3, float* __restrict__ xmacc) {
  __shared__ float us[8][32], vs[8][32];
  __shared__ float red[4][64][8];
  int blk = blockIdx.x;
  int fc = blk & 7, kc = blk >> 3;
  int t = threadIdx.x;
  {
    int b = t >> 5, k = t & 31;
    us[b][k] = uv[b * HID + kc * 32 + k];
    vs[b][k] = uv[BB * HID + b * HID + kc * 32 + k];
  }
  __syncthreads();
  int f = fc * 64 + (t & 63);
  int ks = t >> 6;                 // 0..3
  float acc[8] = {0, 0, 0, 0, 0, 0, 0, 0};
#pragma unroll
  for (int j = 0; j < 8; ++j) {
    int kl = ks * 8 + j;           // 0..31
    int k = kc * 32 + kl;
    float wr = Wrel3[k * HID + f];
    float wo = Wroot3[k * HID + f];
#pragma unroll
    for (int b = 0; b < 8; ++b)
      acc[b] += us[b][kl] * wr + vs[b][kl] * wo;
  }
#pragma unroll
  for (int b = 0; b < 8; ++b) red[ks][t & 63][b] = acc[b];
  __syncthreads();
  if (ks == 0) {
    int fl = t & 63;
#pragma unroll
    for (int b = 0; b < 8; ++b) {
      float v = red[0][fl][b] + red[1][fl][b] + red[2][fl][b] + red[3][fl][b];
      atomicAdd(&xmacc[b * HID + f], v);
    }
  }
}

// ---------------------------------------------------------------------------
// Kernel G3: lin1 split-K partials; xm = 0.5*xmacc + brel3 at staging.
// ---------------------------------------------------------------------------
__global__ __launch_bounds__(256) void lin1_part(
    const float* __restrict__ xmacc, const float* __restrict__ brel3,
    const float* __restrict__ Wlin1, float* __restrict__ h2acc) {
  __shared__ float xs[8][32];
  __shared__ float red[4][64][8];
  int blk = blockIdx.x;
  int fc = blk & 7, kc = blk >> 3;
  int t = threadIdx.x;
  {
    int b = t >> 5, k = t & 31;
    xs[b][k] = 0.5f * xmacc[b * HID + kc * 32 + k] + brel3[kc * 32 + k];
  }
  __syncthreads();
  int f = fc * 64 + (t & 63);
  int ks = t >> 6;
  float acc[8] = {0, 0, 0, 0, 0, 0, 0, 0};
#pragma unroll
  for (int j = 0; j < 8; ++j) {
    int kl = ks * 8 + j;
    int k = kc * 32 + kl;
    float w = Wlin1[k * HID + f];
#pragma unroll
    for (int b = 0; b < 8; ++b)
      acc[b] += xs[b][kl] * w;
  }
#pragma unroll
  for (int b = 0; b < 8; ++b) red[ks][t & 63][b] = acc[b];
  __syncthreads();
  if (ks == 0) {
    int fl = t & 63;
#pragma unroll
    for (int b = 0; b < 8; ++b) {
      float v = red[0][fl][b] + red[1][fl][b] + red[2][fl][b] + red[3][fl][b];
      atomicAdd(&h2acc[b * HID + f], v);
    }
  }
}

// ---------------------------------------------------------------------------
// Kernel G4: logits + log_softmax; h2 = relu(h2acc + blin1) at staging.
// ---------------------------------------------------------------------------
__global__ __launch_bounds__(256) void head(
    const float* __restrict__ h2acc, const float* __restrict__ blin1,
    const float* __restrict__ Wlin2, const float* __restrict__ blin2,
    float* __restrict__ dout) {
  __shared__ float hs[HID];
  __shared__ float lg[16];
  __shared__ float lse;
  int b = blockIdx.x, t = threadIdx.x;
  for (int i = t; i < HID; i += 256)
    hs[i] = fmaxf(h2acc[b * HID + i] + blin1[i], 0.f);
  __syncthreads();
  int wave = t >> 6, lane = t & 63;
  for (int o = wave; o < OUTC; o += 4) {
    float acc = 0.f;
    for (int k = lane; k < HID; k += 64)
      acc += hs[k] * Wlin2[k * OUTC + o];
#pragma unroll
    for (int off = 32; off; off >>= 1) acc += __shfl_down(acc, off, 64);
    if (lane == 0) lg[o] = acc + blin2[o];
  }
  __syncthreads();
  if (t == 0) {
    float m = lg[0];
    for (int o = 1; o < OUTC; ++o) m = fmaxf(m, lg[o]);
    float se = 0.f;
    for (int o = 0; o < OUTC; ++o) se += expf(lg[o] - m);
    lse = m + logf(se);
  }
  __syncthreads();
  if (t < OUTC) dout[b * OUTC + t] = lg[t] - lse;
}

// ---------------------------------------------------------------------------
// Launcher
// ---------------------------------------------------------------------------
extern "C" void kernel_launch(void* const* d_in, const int* in_sizes, int n_in,
                              void* d_out, int out_size, void* d_ws, size_t ws_size,
                              hipStream_t stream) {
  const float* x      = (const float*)d_in[0];
  const int*   ei     = (const int*)d_in[1];
  const float* ew     = (const float*)d_in[3];
  const float* Wrel1  = (const float*)d_in[4];
  const float* brel1  = (const float*)d_in[5];
  const float* Wroot1 = (const float*)d_in[6];
  const float* Wpool  = (const float*)d_in[7];
  const float* bpool  = (const float*)d_in[8];
  const float* Wrel3  = (const float*)d_in[9];
  const float* brel3  = (const float*)d_in[10];
  const float* Wroot3 = (const float*)d_in[11];
  const float* Wlin1  = (const float*)d_in[12];
  const float* blin1  = (const float*)d_in[13];
  const float* Wlin2  = (const float*)d_in[14];
  const float* blin2  = (const float*)d_in[15];
  float* out = (float*)d_out;
  float* ws  = (float*)d_ws;

  // workspace layout (float units)
  float* outp  = ws + 32768;                // [32768, 40960)  (old dw slot unused)
  float* oadj  = outp + 8192;               // [40960, 40992)
  float* ssacc = oadj + 32;                 // [40992, 41024)
  float* mden  = ssacc + 32;                // [41024, 41032)
  int*   deg   = (int*)(mden + 8);          // [41032, 73800)  zero-region end
  int*   off   = deg + 32768;               // [73800, 106568)
  ushort* Ab   = (ushort*)(ws + 106568);    // 32768x256 bf16  [106568, 4300872)
  ushort* Bb   = (ushort*)(ws + 4300872);   // 512x256 bf16    [4300872, 4366408)
  ushort* hbf  = (ushort*)(ws + 4366408);   // 32768x512 bf16  [4366408, 12755016)
  float* xmacc = ws + 12755016;             // 4096
  float* h2acc = xmacc + 4096;              // 4096
  // aliases (lifetimes by stream order):
  int*   ebs   = (int*)(ws + 4366408);      // inside h region; dead before gemm writes h
  float* ebw   = ws + 4890696;              // inside h region
  float* s     = ws + 106568;               // overlays Ab; Ab dead after gemm
  float* uv    = (float*)deg;               // deg dead after gather_agg

  const int* src = ei;
  const int* dst = ei + BE;

  hipMemsetAsync(ws, 0, (size_t)73800 * sizeof(float), stream);
  hipMemsetAsync(xmacc, 0, (size_t)8192 * sizeof(float), stream);
  hipMemsetAsync(out + 80, 0, 2 * sizeof(float), stream);

  edge_count <<<64, 256, 0, stream>>>(dst, deg);
  scan_kernel<<<1, 1024, 0, stream>>>(deg, off);
  edge_bucket<<<64, 256, 0, stream>>>(src, dst, ew, off, ebs, ebw);
  gather_agg <<<BN / 4, 256, 0, stream>>>(off, deg, ebs, ebw, x, Ab);
  cast_x     <<<4096, 256, 0, stream>>>(x, Ab);
  cast_w     <<<512, 256, 0, stream>>>(Wrel1, Wroot1, Bb);
  gemm_mfma  <<<1024, 256, 0, stream>>>(Ab, Bb, brel1, hbf);
  pool_softmax<<<BN / 4, 256, 0, stream>>>(hbf, Wpool, bpool, s, out + 82);
  edge_pass2 <<<BB * 64, 256, 0, stream>>>(src, dst, ew, s, oadj, mden);
  node_acc   <<<BN / 256, 256, 0, stream>>>(hbf, s, outp, ssacc);
  finalize_a <<<BB, 256, 0, stream>>>(outp, oadj, ssacc, mden, uv, out);
  conv3_part <<<128, 256, 0, stream>>>(uv, Wrel3, Wroot3, xmacc);
  lin1_part  <<<128, 256, 0, stream>>>(xmacc, brel3, Wlin1, h2acc);
  head       <<<BB, 256, 0, stream>>>(h2acc, blin1, Wlin2, blin2, out);
}